// Round 1
// baseline (783.826 us; speedup 1.0000x reference)
//
#include <hip/hip_runtime.h>
#include <hip/hip_bf16.h>
#include <math.h>

typedef unsigned short ushort;
typedef unsigned int uint;

// Sizes (fixed by the reference problem)
#define NV 200     // N nodes
#define DEG 199
#define HID 96
#define KG 20      // groups / one-hot width
#define MG 10      // group size
#define AJR 30
#define NH 4
#define HD 118     // HID + 2 + K
#define DM 472     // NH*HD
#define NN 40000   // N*N

// Workspace layout (float units).
#define WS_BASE   0
#define WS_H1     19200
#define WS_H2     38400
#define WS_HFULL  57600
#define WS_GMEAN  81200
#define WS_W0S    83560
#define WS_W1S    139256
#define WS_KHF    194952
#define WS_VHF    289352
#define WS_B1     383752  // after k_SC: reused for C (softmax row consts, 160000 floats)
#define WS_B2     478152
#define WS_SC1    572552
#define WS_SC2    732552
#define WS_Z      892552             // Z fp32: 4*224*472 = 422,912 floats
#define WS_ZT     1315464            // ZT bf16: 512*896 ushorts = 229,376 floats

// Output layout (floats)
#define OFF_H   18880000
#define OFF_HF  18899200
#define OFF_Q   18922800

typedef __attribute__((ext_vector_type(8))) short short8v;
typedef __attribute__((ext_vector_type(4))) float float4v;

__device__ __forceinline__ float bf2f(uint u) {
  return __uint_as_float(u << 16);
}
__device__ __forceinline__ ushort f2bf(float f) {
  uint u = __float_as_uint(f);
  uint r = (u + 0x7fffu + ((u >> 16) & 1u)) >> 16;  // RNE
  return (ushort)r;
}
__device__ __forceinline__ uint packbf(float a, float b) {
  __hip_bfloat162 h2 = __float22bfloat162_rn(make_float2(a, b));
  union { __hip_bfloat162 h; uint u; } c;
  c.h = h2;
  return c.u;
}

// ---------------------------------------------------------------------------
// A: iteration-invariant part of the GCN update
// ---------------------------------------------------------------------------
__global__ __launch_bounds__(256) void k_base(
    const float* __restrict__ x, const float* __restrict__ dmat,
    const float* __restrict__ label,
    const float* __restrict__ l0w, const float* __restrict__ l0b,
    const float* __restrict__ l1w, const float* __restrict__ l1b,
    const float* __restrict__ l2b, const float* __restrict__ l3b,
    const float* __restrict__ l4w, const float* __restrict__ l4b,
    const float* __restrict__ l5w, const float* __restrict__ l5b,
    float* __restrict__ base) {
  int i = blockIdx.x; int t = threadIdx.x;
  int g = i / MG;
  __shared__ float sv[256];
  __shared__ float sn2[9];
  float v = -1.0f;
  if (t < DEG) {
    int u = (t < i) ? t : t + 1;
    if (u / MG != g) v = dmat[i * DEG + t];
  }
  sv[t] = v;
  __syncthreads();
  for (int k2 = 2; k2 <= 256; k2 <<= 1) {
    for (int jj = k2 >> 1; jj > 0; jj >>= 1) {
      int ixj = t ^ jj;
      if (ixj > t) {
        float a = sv[t], b = sv[ixj];
        bool sw = ((t & k2) == 0) ? (a < b) : (a > b);
        if (sw) { sv[t] = b; sv[ixj] = a; }
      }
      __syncthreads();
    }
  }
  if (t == 0) {
    float tmp[9];
    for (int q = 0; q < 9; q++) tmp[q] = dmat[i * DEG + MG * g + q];
    for (int a2 = 1; a2 < 9; a2++) {
      float key = tmp[a2]; int b2 = a2 - 1;
      while (b2 >= 0 && tmp[b2] < key) { tmp[b2 + 1] = tmp[b2]; b2--; }
      tmp[b2 + 1] = key;
    }
    for (int q = 0; q < 9; q++) sn2[q] = tmp[q];
  }
  __syncthreads();
  if (t < HID) {
    float acc = l0b[t] + l1b[t] + l2b[t] + l3b[t] + l4b[t] + l5b[t];
    acc += x[i * 2 + 0] * l0w[t] + x[i * 2 + 1] * l0w[HID + t];
    for (int k = 0; k < KG; k++) acc += label[i * KG + k] * l1w[k * HID + t];
    for (int q = 0; q < AJR; q++) acc += sv[q] * l4w[q * HID + t];
    for (int q = 0; q < 9; q++) acc += sn2[q] * l5w[q * HID + t];
    base[i * HID + t] = acc;
  }
}

// ---------------------------------------------------------------------------
// B: one GCN step
// ---------------------------------------------------------------------------
__global__ __launch_bounds__(192) void k_gcn(
    const float* __restrict__ hin, const float* __restrict__ base,
    const float* __restrict__ w, const float* __restrict__ l2w,
    const float* __restrict__ l3w, float* __restrict__ hout) {
  int i = blockIdx.x; int t = threadIdx.x;
  int g = i / MG;
  __shared__ float n1[HID], n2[HID];
  if (t < HID) {
    float acc = 0.f, wsum = 0.f;
    for (int j = 0; j < DEG; j++) {
      int u = (j < i) ? j : j + 1;
      if (u / MG != g) {
        float wj = w[i * DEG + j];
        acc += wj * hin[u * HID + t];
        wsum += wj;
      }
    }
    n1[t] = acc / wsum;
  } else if (t < 2 * HID) {
    int dd = t - HID;
    float acc = 0.f, wsum = 0.f;
    for (int u = MG * g; u < MG * g + MG; u++) {
      if (u == i) continue;
      int j = (u < i) ? u : u - 1;
      float wj = w[i * DEG + j];
      acc += wj * hin[u * HID + dd];
      wsum += wj;
    }
    n2[dd] = acc / wsum;
  }
  __syncthreads();
  if (t < HID) {
    float acc = base[i * HID + t];
    for (int dd = 0; dd < HID; dd++)
      acc += n1[dd] * l2w[dd * HID + t] + n2[dd] * l3w[dd * HID + t];
    hout[i * HID + t] = fmaxf(acc, 0.f);
  }
}

// ---------------------------------------------------------------------------
// C1: h_full assembly (+ h, h_full outputs)
// ---------------------------------------------------------------------------
__global__ __launch_bounds__(128) void k_hfull(
    const float* __restrict__ h, const float* __restrict__ x,
    const float* __restrict__ label, const int* __restrict__ remain_step,
    float* __restrict__ hfull, float* __restrict__ out_h,
    float* __restrict__ out_hf) {
  int i = blockIdx.x; int t = threadIdx.x;
  if (t < HD) {
    float v;
    if (t < HID) {
      int p = *remain_step;
      int t2 = t & ~1;
      float div = expf(-(float)t2 * (logf(10000.f) / (float)HID));
      float ang = (float)p * div;
      float pe = (t & 1) ? cosf(ang) : sinf(ang);
      float hv = h[i * HID + t];
      out_h[i * HID + t] = hv;
      v = hv + pe;
    } else if (t < HID + 2) {
      v = x[i * 2 + (t - HID)];
    } else {
      v = label[i * KG + (t - HID - 2)];
    }
    hfull[i * HD + t] = v;
    out_hf[i * HD + t] = v;
  }
}

// C2: group means of h_full
__global__ __launch_bounds__(128) void k_gmean(
    const float* __restrict__ hfull, float* __restrict__ gmean) {
  int g = blockIdx.x; int t = threadIdx.x;
  if (t < HD) {
    float s = 0.f;
    for (int q = 0; q < MG; q++) s += hfull[(g * MG + q) * HD + t];
    gmean[g * HD + t] = s * 0.1f;
  }
}

// D1: sum of the 4 118-row blocks of mha_w{0,1}
__global__ __launch_bounds__(256) void k_wsum(
    const float* __restrict__ w0, const float* __restrict__ w1,
    float* __restrict__ W0s, float* __restrict__ W1s) {
  int idx = blockIdx.x * blockDim.x + threadIdx.x;
  if (idx < HD * DM) {
    int dp = idx / DM, c = idx - dp * DM;
    W0s[idx] = w0[dp * DM + c] + w0[(HD + dp) * DM + c] +
               w0[(2 * HD + dp) * DM + c] + w0[(3 * HD + dp) * DM + c];
    W1s[idx] = w1[dp * DM + c] + w1[(HD + dp) * DM + c] +
               w1[(2 * HD + dp) * DM + c] + w1[(3 * HD + dp) * DM + c];
  }
}

// D2: khf / vhf
__global__ __launch_bounds__(256) void k_kv(
    const float* __restrict__ hfull, const float* __restrict__ W0s,
    const float* __restrict__ b0v, const float* __restrict__ W1s,
    const float* __restrict__ b1v, float* __restrict__ khf,
    float* __restrict__ vhf) {
  int i = blockIdx.x; int t = threadIdx.x;
  __shared__ float hr[HD];
  if (t < HD) hr[t] = hfull[i * HD + t];
  __syncthreads();
  for (int c = t; c < DM; c += 256) {
    float a0 = b0v[c], a1 = b1v[c];
    for (int dd = 0; dd < HD; dd++) {
      float hv = hr[dd];
      a0 += hv * W0s[dd * DM + c];
      a1 += hv * W1s[dd * DM + c];
    }
    khf[i * DM + c] = a0;
    vhf[i * DM + c] = a1;
  }
}

// D3: B1/B2 (query decomposition)
__global__ __launch_bounds__(256) void k_B(
    const float* __restrict__ hfull, const float* __restrict__ gmean,
    const float* __restrict__ w0, const float* __restrict__ b0v,
    float* __restrict__ B1, float* __restrict__ B2) {
  int i = blockIdx.x; int t = threadIdx.x; int g = i / MG;
  __shared__ float hr[HD], gr[HD];
  if (t < HD) { hr[t] = hfull[i * HD + t]; gr[t] = gmean[g * HD + t]; }
  __syncthreads();
  for (int c = t; c < DM; c += 256) {
    float a1 = 0.f, a2 = b0v[c];
    for (int dd = 0; dd < HD; dd++) {
      a1 += hr[dd] * w0[dd * DM + c] + gr[dd] * w0[(2 * HD + dd) * DM + c];
      a2 += hr[dd] * w0[(HD + dd) * DM + c] + gr[dd] * w0[(3 * HD + dd) * DM + c];
    }
    B1[i * DM + c] = a1;
    B2[i * DM + c] = a2;
  }
}

// D4: score components SC1/SC2, pre-scaled by (1/sqrt(HD))*log2(e)
__global__ __launch_bounds__(256) void k_SC(
    const float* __restrict__ B1, const float* __restrict__ B2,
    const float* __restrict__ khf, float* __restrict__ SC1,
    float* __restrict__ SC2) {
  int i = blockIdx.x; int t = threadIdx.x;
  const float scl = 1.4426950408889634f / sqrtf((float)HD);
  __shared__ float b1r[DM], b2r[DM];
  for (int c = t; c < DM; c += 256) { b1r[c] = B1[i * DM + c]; b2r[c] = B2[i * DM + c]; }
  __syncthreads();
  for (int p = t; p < NH * NV; p += 256) {
    int h = p / NV, k = p - h * NV;
    float s1a = 0.f, s2a = 0.f;
    for (int dd = 0; dd < HD; dd++) {
      float kv = khf[k * DM + h * HD + dd];
      s1a += b1r[h * HD + dd] * kv;
      s2a += b2r[h * HD + dd] * kv;
    }
    SC1[h * NN + i * NV + k] = s1a * scl;
    SC2[h * NN + i * NV + k] = s2a * scl;
  }
}

// D5: softmax row constants C[h][i][j] = m + log2(l), coalesced row scans.
__global__ __launch_bounds__(256) void k_ml(
    const float* __restrict__ SC1, const float* __restrict__ SC2,
    float* __restrict__ C) {
  int i = blockIdx.x, h = blockIdx.y;
  int t = threadIdx.x;
  __shared__ float s1s[224];
  for (int k = t; k < 224; k += 256)
    s1s[k] = (k < NV) ? SC1[h * NN + i * NV + k] : -1e30f;
  __syncthreads();
  int l = t & 31;
  int g = t >> 5;
  const float* s2b = SC2 + h * NN;
  for (int it = 0; it < 25; ++it) {
    int j = it * 8 + g;
    const float* row = s2b + j * NV;
    float v[7];
#pragma unroll
    for (int e = 0; e < 7; ++e) {
      int k = l + 32 * e;
      v[e] = (k < NV) ? (s1s[k] + row[k]) : -1e30f;
    }
    float m = v[0];
#pragma unroll
    for (int e = 1; e < 7; ++e) m = fmaxf(m, v[e]);
#pragma unroll
    for (int off = 16; off > 0; off >>= 1) m = fmaxf(m, __shfl_xor(m, off, 32));
    float s = 0.f;
#pragma unroll
    for (int e = 0; e < 7; ++e) s += exp2f(v[e] - m);
#pragma unroll
    for (int off = 16; off > 0; off >>= 1) s += __shfl_xor(s, off, 32);
    if (l == 0) C[h * NN + i * NV + j] = m + log2f(s);
  }
}

// ---------------------------------------------------------------------------
// E1: Z[h][k][c] = sum_d vhf[k][h*HD+d] * w3[(h*HD+d)*DM + c]  (fp32)
// Grid (NV, NH).
// ---------------------------------------------------------------------------
__global__ __launch_bounds__(256) void k_Z(
    const float* __restrict__ vhf, const float* __restrict__ w3,
    float* __restrict__ Z) {
  int k = blockIdx.x, h = blockIdx.y;
  int t = threadIdx.x;
  __shared__ float vr[HD];
  if (t < HD) vr[t] = vhf[k * DM + h * HD + t];
  __syncthreads();
  for (int c = t; c < DM; c += 256) {
    float a = 0.f;
    for (int d = 0; d < HD; ++d) a += vr[d] * w3[(h * HD + d) * DM + c];
    Z[((size_t)h * 224 + k) * DM + c] = a;
  }
}

// E2: ZT[c][h*224+kk] = bf16(Z[h][kk][c]) zero-padded (c>=472 or kk>=200). 512x896.
__global__ __launch_bounds__(256) void k_ZT(
    const float* __restrict__ Z, ushort* __restrict__ ZT) {
  int idx = blockIdx.x * 256 + threadIdx.x;  // < 512*896
  if (idx < 512 * 896) {
    int c = idx / 896, kp = idx - c * 896;
    int h = kp / 224, kk = kp - h * 224;
    ushort v = 0;
    if (c < DM && kk < NV) v = f2bf(Z[((size_t)h * 224 + kk) * DM + c]);
    ZT[idx] = v;
  }
}

// ---------------------------------------------------------------------------
// F (v2): fused attention+output GEMM, full output width per block.
// S[b=(i,j)][c] = sum_{h,k} [exp2(SC1[h,i,k]+SC2[h,j,k]-C[h,i,j])
//                          + exp2(SC1[h,j,k]+SC2[h,i,k]-C[h,j,i])] * Z[h][k][c]
//               + 2*b3[c]
// Key change vs v1: one block covers ALL 512 (472 live) output columns, so the
// VALU-heavy P-tile (exp2+pack) is computed ONCE into LDS and shared by all
// 8 waves, instead of being recomputed per 128-col tile (was 4x redundant).
// Block: 512 threads = 8 waves; 64 rows x 512 cols; wave w owns cols w*64..+63.
// K' = 4 heads x 224 (zero-padded ZT), stepped 32 at a time.
// ---------------------------------------------------------------------------
__global__ __launch_bounds__(512) void k_sfused2(
    const float* __restrict__ SC1, const float* __restrict__ SC2,
    const float* __restrict__ C, const ushort* __restrict__ ZT,
    const float* __restrict__ b3, float* __restrict__ outS) {
  int t = threadIdx.x;
  int b0 = blockIdx.x * 64;              // NN = 625*64 exactly, no row guards
  int lane = t & 63, wm = t >> 6;        // wave 0..7
  int frow = lane & 15, quad = lane >> 4;
  int wcb = wm * 64;                     // wave's column base
  // LDS: padded stride 40 ushorts (80B) keeps b128 ops 16B-aligned and
  // spreads frow-strided reads over all banks (80B = 20 banks).
  __shared__ __align__(16) ushort As[64 * 40];    // P tile, bf16
  __shared__ __align__(16) ushort Bs[512 * 40];   // Z^T tile, bf16
  __shared__ __align__(16) float S1i[2][224];
  __shared__ __align__(16) float S2i[2][224];
  __shared__ float CijS[64], CjiS[64];
  int i0 = b0 / NV;
  int i1 = (b0 + 63) / NV;               // <= 199 always
  // P-gen work assignment: thread -> (row r, 4 consecutive k)
  int r = t >> 3;                        // 0..63
  int kq = (t & 7) * 4;                  // 0,4,...,28
  int bP = b0 + r;
  int iP = bP / NV;
  int jP = bP - iP * NV;
  int isel = iP - i0;                    // 0 or 1
  float4v acc[4][4];
#pragma unroll
  for (int m = 0; m < 4; ++m)
#pragma unroll
    for (int n = 0; n < 4; ++n) acc[m][n] = (float4v)(0.f);

  for (int h = 0; h < NH; ++h) {
    __syncthreads();  // all waves done reading S1i/S2i/CijS of previous head
    if (t < 224) {
      bool v = t < NV;
      int o0 = h * NN + i0 * NV + t;
      int o1 = h * NN + i1 * NV + t;
      S1i[0][t] = v ? SC1[o0] : 0.f;
      S2i[0][t] = v ? SC2[o0] : 0.f;
      S1i[1][t] = v ? SC1[o1] : 0.f;
      S2i[1][t] = v ? SC2[o1] : 0.f;
    } else if (t >= 256 && t < 320) {
      int rr = t - 256;
      int b = b0 + rr;
      int ii = b / NV, jv = b - ii * NV;
      CijS[rr] = C[h * NN + b];
      CjiS[rr] = C[h * NN + jv * NV + ii];
    }
    __syncthreads();
    float ci = CijS[r], cj = CjiS[r];
    const float* pj1 = SC1 + h * NN + jP * NV;
    const float* pj2 = SC2 + h * NN + jP * NV;
    const ushort* zb = ZT + h * 224;

    for (int ks = 0; ks < 7; ++ks) {
      // --- issue B-tile loads early (hide L2 latency under exp2) ---
      uint4 bq[4];
#pragma unroll
      for (int qq = 0; qq < 4; ++qq) {
        int li = qq * 512 + t;           // 0..2047
        int c = li >> 2;                 // 0..511
        int ko = (li & 3) * 8;           // 0,8,16,24 (ushorts)
        bq[qq] = *(const uint4*)(zb + (size_t)c * 896 + ks * 32 + ko);
      }
      // --- P values for this thread's 4 elements ---
      int kb = ks * 32 + kq;
      uint pk0 = 0, pk1 = 0;
      if (kb < NV) {                     // NV%4==0: granule fully valid or not
        float4 a1 = *(const float4*)(pj1 + kb);
        float4 a2 = *(const float4*)(pj2 + kb);
        float4 t1 = *(const float4*)&S1i[isel][kb];
        float4 u1 = *(const float4*)&S2i[isel][kb];
        float p0 = exp2f(t1.x + a2.x - ci) + exp2f(a1.x + u1.x - cj);
        float p1 = exp2f(t1.y + a2.y - ci) + exp2f(a1.y + u1.y - cj);
        float p2 = exp2f(t1.z + a2.z - ci) + exp2f(a1.z + u1.z - cj);
        float p3 = exp2f(t1.w + a2.w - ci) + exp2f(a1.w + u1.w - cj);
        pk0 = packbf(p0, p1);
        pk1 = packbf(p2, p3);
      }
      __syncthreads();  // previous step's MFMA reads of As/Bs complete
      *(uint2*)&As[r * 40 + kq] = make_uint2(pk0, pk1);
#pragma unroll
      for (int qq = 0; qq < 4; ++qq) {
        int li = qq * 512 + t;
        int c = li >> 2;
        int ko = (li & 3) * 8;
        *(uint4*)&Bs[c * 40 + ko] = bq[qq];
      }
      __syncthreads();
      // --- MFMA: 4 m-frags x 4 n-frags per wave ---
      short8v af[4];
#pragma unroll
      for (int m = 0; m < 4; ++m)
        af[m] = *(const short8v*)&As[(m * 16 + frow) * 40 + quad * 8];
#pragma unroll
      for (int n = 0; n < 4; ++n) {
        int cb = wcb + n * 16;
        if (cb < DM) {                   // wave-uniform: skip dead col frags
          short8v bf = *(const short8v*)&Bs[(cb + frow) * 40 + quad * 8];
#pragma unroll
          for (int m = 0; m < 4; ++m)
            acc[m][n] = __builtin_amdgcn_mfma_f32_16x16x32_bf16(
                af[m], bf, acc[m][n], 0, 0, 0);
        }
      }
    }
  }
  // epilogue: C/D layout col=lane&15, row=quad*4+reg
#pragma unroll
  for (int n = 0; n < 4; ++n) {
    int c = wcb + n * 16 + frow;
    if (c >= DM) continue;
    float bb = 2.0f * b3[c];
#pragma unroll
    for (int m = 0; m < 4; ++m) {
      int bbase = b0 + m * 16 + quad * 4;
#pragma unroll
      for (int r2 = 0; r2 < 4; ++r2) {
        outS[(size_t)(bbase + r2) * DM + c] = acc[m][n][r2] + bb;
      }
    }
  }
}

// ---------------------------------------------------------------------------
// G: Q_sa = relu(S@v1+b1)@v2 + b2
// ---------------------------------------------------------------------------
__global__ __launch_bounds__(256) void k_qsa(
    const float* __restrict__ S, const float* __restrict__ v1w,
    const float* __restrict__ v1b, const float* __restrict__ v2w,
    const float* __restrict__ v2b, float* __restrict__ outQ) {
  __shared__ float Ss[64][9];
  __shared__ float V1s[8][48];
  __shared__ float Ts[64][49];
  int t = threadIdx.x;
  int b0 = blockIdx.x * 64;
  int ty = t >> 4, tx = t & 15;
  int lr = t >> 2, lk = (t & 3) * 2;
  float acc[4][3];
#pragma unroll
  for (int y = 0; y < 4; y++)
#pragma unroll
    for (int xx = 0; xx < 3; xx++) acc[y][xx] = 0.f;
  for (int k0 = 0; k0 < DM; k0 += 8) {
    __syncthreads();
    Ss[lr][lk] = S[(size_t)(b0 + lr) * DM + k0 + lk];
    Ss[lr][lk + 1] = S[(size_t)(b0 + lr) * DM + k0 + lk + 1];
    if (t < 192) {
      int e = t * 2; int kk = e / 48, c = e - kk * 48;
      V1s[kk][c] = v1w[(k0 + kk) * 48 + c];
      V1s[kk][c + 1] = v1w[(k0 + kk) * 48 + c + 1];
    }
    __syncthreads();
#pragma unroll
    for (int kk = 0; kk < 8; kk++) {
      float a0 = Ss[ty * 4 + 0][kk], a1 = Ss[ty * 4 + 1][kk],
            a2 = Ss[ty * 4 + 2][kk], a3 = Ss[ty * 4 + 3][kk];
      float w0_ = V1s[kk][tx * 3 + 0], w1_ = V1s[kk][tx * 3 + 1],
            w2_ = V1s[kk][tx * 3 + 2];
      acc[0][0] += a0 * w0_; acc[0][1] += a0 * w1_; acc[0][2] += a0 * w2_;
      acc[1][0] += a1 * w0_; acc[1][1] += a1 * w1_; acc[1][2] += a1 * w2_;
      acc[2][0] += a2 * w0_; acc[2][1] += a2 * w1_; acc[2][2] += a2 * w2_;
      acc[3][0] += a3 * w0_; acc[3][1] += a3 * w1_; acc[3][2] += a3 * w2_;
    }
  }
#pragma unroll
  for (int y = 0; y < 4; y++)
#pragma unroll
    for (int xx = 0; xx < 3; xx++)
      Ts[ty * 4 + y][tx * 3 + xx] = fmaxf(acc[y][xx] + v1b[tx * 3 + xx], 0.f);
  __syncthreads();
  if (t < 64) {
    float q = v2b[0];
    for (int c = 0; c < 48; c++) q += Ts[t][c] * v2w[c];
    outQ[b0 + t] = q;
  }
}

// ---------------------------------------------------------------------------
extern "C" void kernel_launch(void* const* d_in, const int* in_sizes, int n_in,
                              void* d_out, int out_size, void* d_ws,
                              size_t ws_size, hipStream_t stream) {
  const float* x = (const float*)d_in[0];
  const float* label = (const float*)d_in[1];
  const float* h0 = (const float*)d_in[2];
  const float* w = (const float*)d_in[3];
  const float* dmat = (const float*)d_in[4];
  const float* l0w = (const float*)d_in[5];
  const float* l0b = (const float*)d_in[6];
  const float* l1w = (const float*)d_in[7];
  const float* l1b = (const float*)d_in[8];
  const float* l2w = (const float*)d_in[9];
  const float* l2b = (const float*)d_in[10];
  const float* l3w = (const float*)d_in[11];
  const float* l3b = (const float*)d_in[12];
  const float* l4w = (const float*)d_in[13];
  const float* l4b = (const float*)d_in[14];
  const float* l5w = (const float*)d_in[15];
  const float* l5b = (const float*)d_in[16];
  const float* w0 = (const float*)d_in[17];
  const float* b0v = (const float*)d_in[18];
  const float* w1 = (const float*)d_in[19];
  const float* b1v = (const float*)d_in[20];
  const float* w3 = (const float*)d_in[21];
  const float* b3 = (const float*)d_in[22];
  const float* v1w = (const float*)d_in[23];
  const float* v1b = (const float*)d_in[24];
  const float* v2w = (const float*)d_in[25];
  const float* v2b = (const float*)d_in[26];
  const int* remain_step = (const int*)d_in[29];

  float* ws = (float*)d_ws;
  float* base = ws + WS_BASE;
  float* h1 = ws + WS_H1;
  float* h2 = ws + WS_H2;
  float* hfull = ws + WS_HFULL;
  float* gmean = ws + WS_GMEAN;
  float* W0s = ws + WS_W0S;
  float* W1s = ws + WS_W1S;
  float* khf = ws + WS_KHF;
  float* vhf = ws + WS_VHF;
  float* B1 = ws + WS_B1;
  float* B2 = ws + WS_B2;
  float* SC1 = ws + WS_SC1;
  float* SC2 = ws + WS_SC2;
  float* Z = ws + WS_Z;
  ushort* ZT = (ushort*)(ws + WS_ZT);
  float* C = ws + WS_B1;  // reuses B1/B2 slots after k_SC

  float* outS = (float*)d_out;
  float* outH = outS + OFF_H;
  float* outHF = outS + OFF_HF;
  float* outQ = outS + OFF_Q;

  k_base<<<NV, 256, 0, stream>>>(x, dmat, label, l0w, l0b, l1w, l1b, l2b, l3b,
                                 l4w, l4b, l5w, l5b, base);
  k_gcn<<<NV, 192, 0, stream>>>(h0, base, w, l2w, l3w, h1);
  k_gcn<<<NV, 192, 0, stream>>>(h1, base, w, l2w, l3w, h2);
  k_hfull<<<NV, 128, 0, stream>>>(h2, x, label, remain_step, hfull, outH, outHF);
  k_gmean<<<KG, 128, 0, stream>>>(hfull, gmean);
  k_wsum<<<(HD * DM + 255) / 256, 256, 0, stream>>>(w0, w1, W0s, W1s);
  k_kv<<<NV, 256, 0, stream>>>(hfull, W0s, b0v, W1s, b1v, khf, vhf);
  k_Z<<<dim3(NV, NH), 256, 0, stream>>>(vhf, w3, Z);
  k_ZT<<<(512 * 896 + 255) / 256, 256, 0, stream>>>(Z, ZT);
  k_B<<<NV, 256, 0, stream>>>(hfull, gmean, w0, b0v, B1, B2);
  k_SC<<<NV, 256, 0, stream>>>(B1, B2, khf, SC1, SC2);
  k_ml<<<dim3(NV, NH), 256, 0, stream>>>(SC1, SC2, C);
  k_sfused2<<<NN / 64, 512, 0, stream>>>(SC1, SC2, C, ZT, b3, outS);
  k_qsa<<<NN / 64, 256, 0, stream>>>(outS, v1w, v1b, v2w, v2b, outQ);
}

// Round 2
// 709.159 us; speedup vs baseline: 1.1053x; 1.1053x over previous
//
#include <hip/hip_runtime.h>
#include <hip/hip_bf16.h>
#include <math.h>

typedef unsigned short ushort;
typedef unsigned int uint;

// Sizes (fixed by the reference problem)
#define NV 200     // N nodes
#define DEG 199
#define HID 96
#define KG 20      // groups / one-hot width
#define MG 10      // group size
#define AJR 30
#define NH 4
#define HD 118     // HID + 2 + K
#define DM 472     // NH*HD
#define NN 40000   // N*N

// Workspace layout (float units).
#define WS_BASE   0
#define WS_H1     19200
#define WS_H2     38400
#define WS_HFULL  57600
#define WS_GMEAN  81200
#define WS_W0S    83560
#define WS_W1S    139256
#define WS_KHF    194952
#define WS_VHF    289352
#define WS_B1     383752  // after k_SC: reused for C (softmax row consts, 160000 floats)
#define WS_B2     478152
#define WS_SC1    572552
#define WS_SC2    732552
#define WS_Z      892552             // Z fp32: 4*224*472 = 422,912 floats
#define WS_ZT     1315464            // ZT bf16: 512*896 ushorts = 229,376 floats

// Output layout (floats)
#define OFF_H   18880000
#define OFF_HF  18899200
#define OFF_Q   18922800

typedef __attribute__((ext_vector_type(8))) short short8v;
typedef __attribute__((ext_vector_type(4))) float float4v;

__device__ __forceinline__ float bf2f(uint u) {
  return __uint_as_float(u << 16);
}
__device__ __forceinline__ ushort f2bf(float f) {
  uint u = __float_as_uint(f);
  uint r = (u + 0x7fffu + ((u >> 16) & 1u)) >> 16;  // RNE
  return (ushort)r;
}
__device__ __forceinline__ uint packbf(float a, float b) {
  __hip_bfloat162 h2 = __float22bfloat162_rn(make_float2(a, b));
  union { __hip_bfloat162 h; uint u; } c;
  c.h = h2;
  return c.u;
}

// ---------------------------------------------------------------------------
// A: iteration-invariant part of the GCN update
// ---------------------------------------------------------------------------
__global__ __launch_bounds__(256) void k_base(
    const float* __restrict__ x, const float* __restrict__ dmat,
    const float* __restrict__ label,
    const float* __restrict__ l0w, const float* __restrict__ l0b,
    const float* __restrict__ l1w, const float* __restrict__ l1b,
    const float* __restrict__ l2b, const float* __restrict__ l3b,
    const float* __restrict__ l4w, const float* __restrict__ l4b,
    const float* __restrict__ l5w, const float* __restrict__ l5b,
    float* __restrict__ base) {
  int i = blockIdx.x; int t = threadIdx.x;
  int g = i / MG;
  __shared__ float sv[256];
  __shared__ float sn2[9];
  float v = -1.0f;
  if (t < DEG) {
    int u = (t < i) ? t : t + 1;
    if (u / MG != g) v = dmat[i * DEG + t];
  }
  sv[t] = v;
  __syncthreads();
  for (int k2 = 2; k2 <= 256; k2 <<= 1) {
    for (int jj = k2 >> 1; jj > 0; jj >>= 1) {
      int ixj = t ^ jj;
      if (ixj > t) {
        float a = sv[t], b = sv[ixj];
        bool sw = ((t & k2) == 0) ? (a < b) : (a > b);
        if (sw) { sv[t] = b; sv[ixj] = a; }
      }
      __syncthreads();
    }
  }
  if (t == 0) {
    float tmp[9];
    for (int q = 0; q < 9; q++) tmp[q] = dmat[i * DEG + MG * g + q];
    for (int a2 = 1; a2 < 9; a2++) {
      float key = tmp[a2]; int b2 = a2 - 1;
      while (b2 >= 0 && tmp[b2] < key) { tmp[b2 + 1] = tmp[b2]; b2--; }
      tmp[b2 + 1] = key;
    }
    for (int q = 0; q < 9; q++) sn2[q] = tmp[q];
  }
  __syncthreads();
  if (t < HID) {
    float acc = l0b[t] + l1b[t] + l2b[t] + l3b[t] + l4b[t] + l5b[t];
    acc += x[i * 2 + 0] * l0w[t] + x[i * 2 + 1] * l0w[HID + t];
    for (int k = 0; k < KG; k++) acc += label[i * KG + k] * l1w[k * HID + t];
    for (int q = 0; q < AJR; q++) acc += sv[q] * l4w[q * HID + t];
    for (int q = 0; q < 9; q++) acc += sn2[q] * l5w[q * HID + t];
    base[i * HID + t] = acc;
  }
}

// ---------------------------------------------------------------------------
// B: one GCN step
// ---------------------------------------------------------------------------
__global__ __launch_bounds__(192) void k_gcn(
    const float* __restrict__ hin, const float* __restrict__ base,
    const float* __restrict__ w, const float* __restrict__ l2w,
    const float* __restrict__ l3w, float* __restrict__ hout) {
  int i = blockIdx.x; int t = threadIdx.x;
  int g = i / MG;
  __shared__ float n1[HID], n2[HID];
  if (t < HID) {
    float acc = 0.f, wsum = 0.f;
    for (int j = 0; j < DEG; j++) {
      int u = (j < i) ? j : j + 1;
      if (u / MG != g) {
        float wj = w[i * DEG + j];
        acc += wj * hin[u * HID + t];
        wsum += wj;
      }
    }
    n1[t] = acc / wsum;
  } else if (t < 2 * HID) {
    int dd = t - HID;
    float acc = 0.f, wsum = 0.f;
    for (int u = MG * g; u < MG * g + MG; u++) {
      if (u == i) continue;
      int j = (u < i) ? u : u - 1;
      float wj = w[i * DEG + j];
      acc += wj * hin[u * HID + dd];
      wsum += wj;
    }
    n2[dd] = acc / wsum;
  }
  __syncthreads();
  if (t < HID) {
    float acc = base[i * HID + t];
    for (int dd = 0; dd < HID; dd++)
      acc += n1[dd] * l2w[dd * HID + t] + n2[dd] * l3w[dd * HID + t];
    hout[i * HID + t] = fmaxf(acc, 0.f);
  }
}

// ---------------------------------------------------------------------------
// C1: h_full assembly (+ h, h_full outputs)
// ---------------------------------------------------------------------------
__global__ __launch_bounds__(128) void k_hfull(
    const float* __restrict__ h, const float* __restrict__ x,
    const float* __restrict__ label, const int* __restrict__ remain_step,
    float* __restrict__ hfull, float* __restrict__ out_h,
    float* __restrict__ out_hf) {
  int i = blockIdx.x; int t = threadIdx.x;
  if (t < HD) {
    float v;
    if (t < HID) {
      int p = *remain_step;
      int t2 = t & ~1;
      float div = expf(-(float)t2 * (logf(10000.f) / (float)HID));
      float ang = (float)p * div;
      float pe = (t & 1) ? cosf(ang) : sinf(ang);
      float hv = h[i * HID + t];
      out_h[i * HID + t] = hv;
      v = hv + pe;
    } else if (t < HID + 2) {
      v = x[i * 2 + (t - HID)];
    } else {
      v = label[i * KG + (t - HID - 2)];
    }
    hfull[i * HD + t] = v;
    out_hf[i * HD + t] = v;
  }
}

// C2: group means of h_full
__global__ __launch_bounds__(128) void k_gmean(
    const float* __restrict__ hfull, float* __restrict__ gmean) {
  int g = blockIdx.x; int t = threadIdx.x;
  if (t < HD) {
    float s = 0.f;
    for (int q = 0; q < MG; q++) s += hfull[(g * MG + q) * HD + t];
    gmean[g * HD + t] = s * 0.1f;
  }
}

// D1: sum of the 4 118-row blocks of mha_w{0,1}
__global__ __launch_bounds__(256) void k_wsum(
    const float* __restrict__ w0, const float* __restrict__ w1,
    float* __restrict__ W0s, float* __restrict__ W1s) {
  int idx = blockIdx.x * blockDim.x + threadIdx.x;
  if (idx < HD * DM) {
    int dp = idx / DM, c = idx - dp * DM;
    W0s[idx] = w0[dp * DM + c] + w0[(HD + dp) * DM + c] +
               w0[(2 * HD + dp) * DM + c] + w0[(3 * HD + dp) * DM + c];
    W1s[idx] = w1[dp * DM + c] + w1[(HD + dp) * DM + c] +
               w1[(2 * HD + dp) * DM + c] + w1[(3 * HD + dp) * DM + c];
  }
}

// D2: khf / vhf
__global__ __launch_bounds__(256) void k_kv(
    const float* __restrict__ hfull, const float* __restrict__ W0s,
    const float* __restrict__ b0v, const float* __restrict__ W1s,
    const float* __restrict__ b1v, float* __restrict__ khf,
    float* __restrict__ vhf) {
  int i = blockIdx.x; int t = threadIdx.x;
  __shared__ float hr[HD];
  if (t < HD) hr[t] = hfull[i * HD + t];
  __syncthreads();
  for (int c = t; c < DM; c += 256) {
    float a0 = b0v[c], a1 = b1v[c];
    for (int dd = 0; dd < HD; dd++) {
      float hv = hr[dd];
      a0 += hv * W0s[dd * DM + c];
      a1 += hv * W1s[dd * DM + c];
    }
    khf[i * DM + c] = a0;
    vhf[i * DM + c] = a1;
  }
}

// D3: B1/B2 (query decomposition)
__global__ __launch_bounds__(256) void k_B(
    const float* __restrict__ hfull, const float* __restrict__ gmean,
    const float* __restrict__ w0, const float* __restrict__ b0v,
    float* __restrict__ B1, float* __restrict__ B2) {
  int i = blockIdx.x; int t = threadIdx.x; int g = i / MG;
  __shared__ float hr[HD], gr[HD];
  if (t < HD) { hr[t] = hfull[i * HD + t]; gr[t] = gmean[g * HD + t]; }
  __syncthreads();
  for (int c = t; c < DM; c += 256) {
    float a1 = 0.f, a2 = b0v[c];
    for (int dd = 0; dd < HD; dd++) {
      a1 += hr[dd] * w0[dd * DM + c] + gr[dd] * w0[(2 * HD + dd) * DM + c];
      a2 += hr[dd] * w0[(HD + dd) * DM + c] + gr[dd] * w0[(3 * HD + dd) * DM + c];
    }
    B1[i * DM + c] = a1;
    B2[i * DM + c] = a2;
  }
}

// D4: score components SC1/SC2, pre-scaled by (1/sqrt(HD))*log2(e)
__global__ __launch_bounds__(256) void k_SC(
    const float* __restrict__ B1, const float* __restrict__ B2,
    const float* __restrict__ khf, float* __restrict__ SC1,
    float* __restrict__ SC2) {
  int i = blockIdx.x; int t = threadIdx.x;
  const float scl = 1.4426950408889634f / sqrtf((float)HD);
  __shared__ float b1r[DM], b2r[DM];
  for (int c = t; c < DM; c += 256) { b1r[c] = B1[i * DM + c]; b2r[c] = B2[i * DM + c]; }
  __syncthreads();
  for (int p = t; p < NH * NV; p += 256) {
    int h = p / NV, k = p - h * NV;
    float s1a = 0.f, s2a = 0.f;
    for (int dd = 0; dd < HD; dd++) {
      float kv = khf[k * DM + h * HD + dd];
      s1a += b1r[h * HD + dd] * kv;
      s2a += b2r[h * HD + dd] * kv;
    }
    SC1[h * NN + i * NV + k] = s1a * scl;
    SC2[h * NN + i * NV + k] = s2a * scl;
  }
}

// D5: softmax row constants C[h][i][j] = m + log2(l), coalesced row scans.
__global__ __launch_bounds__(256) void k_ml(
    const float* __restrict__ SC1, const float* __restrict__ SC2,
    float* __restrict__ C) {
  int i = blockIdx.x, h = blockIdx.y;
  int t = threadIdx.x;
  __shared__ float s1s[224];
  for (int k = t; k < 224; k += 256)
    s1s[k] = (k < NV) ? SC1[h * NN + i * NV + k] : -1e30f;
  __syncthreads();
  int l = t & 31;
  int g = t >> 5;
  const float* s2b = SC2 + h * NN;
  for (int it = 0; it < 25; ++it) {
    int j = it * 8 + g;
    const float* row = s2b + j * NV;
    float v[7];
#pragma unroll
    for (int e = 0; e < 7; ++e) {
      int k = l + 32 * e;
      v[e] = (k < NV) ? (s1s[k] + row[k]) : -1e30f;
    }
    float m = v[0];
#pragma unroll
    for (int e = 1; e < 7; ++e) m = fmaxf(m, v[e]);
#pragma unroll
    for (int off = 16; off > 0; off >>= 1) m = fmaxf(m, __shfl_xor(m, off, 32));
    float s = 0.f;
#pragma unroll
    for (int e = 0; e < 7; ++e) s += exp2f(v[e] - m);
#pragma unroll
    for (int off = 16; off > 0; off >>= 1) s += __shfl_xor(s, off, 32);
    if (l == 0) C[h * NN + i * NV + j] = m + log2f(s);
  }
}

// ---------------------------------------------------------------------------
// E1: Z[h][k][c] = sum_d vhf[k][h*HD+d] * w3[(h*HD+d)*DM + c]  (fp32)
// Grid (NV, NH).
// ---------------------------------------------------------------------------
__global__ __launch_bounds__(256) void k_Z(
    const float* __restrict__ vhf, const float* __restrict__ w3,
    float* __restrict__ Z) {
  int k = blockIdx.x, h = blockIdx.y;
  int t = threadIdx.x;
  __shared__ float vr[HD];
  if (t < HD) vr[t] = vhf[k * DM + h * HD + t];
  __syncthreads();
  for (int c = t; c < DM; c += 256) {
    float a = 0.f;
    for (int d = 0; d < HD; ++d) a += vr[d] * w3[(h * HD + d) * DM + c];
    Z[((size_t)h * 224 + k) * DM + c] = a;
  }
}

// E2: ZT[c][h*224+kk] = bf16(Z[h][kk][c]) zero-padded (c>=472 or kk>=200). 512x896.
__global__ __launch_bounds__(256) void k_ZT(
    const float* __restrict__ Z, ushort* __restrict__ ZT) {
  int idx = blockIdx.x * 256 + threadIdx.x;  // < 512*896
  if (idx < 512 * 896) {
    int c = idx / 896, kp = idx - c * 896;
    int h = kp / 224, kk = kp - h * 224;
    ushort v = 0;
    if (c < DM && kk < NV) v = f2bf(Z[((size_t)h * 224 + kk) * DM + c]);
    ZT[idx] = v;
  }
}

// ---------------------------------------------------------------------------
// F (v3): fused attention+output GEMM.
// S[b=(i,j)][c] = sum_{h,k} [exp2(SC1[h,i,k]+SC2[h,j,k]-C[h,i,j])
//                          + exp2(SC1[h,j,k]+SC2[h,i,k]-C[h,j,i])] * Z[h][k][c]
//               + 2*b3[c]
// Post-mortem-driven geometry: v2 (512-thread blocks) collapsed to 1 block/CU
// (8 waves x ~140 regs exceed half the VGPR pool) -> barrier/latency bound.
// v3 stays in v1's proven occupancy regime: 256 threads (4 waves), acc[2][8]
// per wave, ~3 blocks/CU. Tile = 64 rows x 256 cols, grid (2, 625):
//   - P tile (64x32) built cooperatively in LDS ONCE per block (16 exp2/thread
//     /step vs v1's 32), consumed by all 4 waves via ds_read_b128.
//   - exp2 redundancy: 2x (across the two col-tile blocks) vs v1's 4x.
// Waves: wm -> (wr=wm&1: 32-row group, wc=wm>>1: 128-col group).
// ---------------------------------------------------------------------------
__global__ __launch_bounds__(256) void k_sfused3(
    const float* __restrict__ SC1, const float* __restrict__ SC2,
    const float* __restrict__ C, const ushort* __restrict__ ZT,
    const float* __restrict__ b3, float* __restrict__ outS) {
  int t = threadIdx.x;
  int c0 = blockIdx.x * 256;             // 0 or 256
  int b0 = blockIdx.y * 64;              // NN = 625*64 exactly, no row guards
  int lane = t & 63, wm = t >> 6;        // wave 0..3
  int frow = lane & 15, quad = lane >> 4;
  int wr = wm & 1;                       // row group: rows wr*32..wr*32+31
  int wcb = (wm >> 1) * 128;             // col group: 128 cols per wave pair
  // LDS: padded stride 40 ushorts (80B) keeps b128 ops 16B-aligned.
  __shared__ __align__(16) ushort As[64 * 40];    // P tile, bf16
  __shared__ __align__(16) ushort Bs[256 * 40];   // Z^T tile, bf16
  __shared__ __align__(16) float S1i[2][224];
  __shared__ __align__(16) float S2i[2][224];
  __shared__ float CijS[64], CjiS[64];
  int i0 = b0 / NV;
  int i1 = (b0 + 63) / NV;               // <= 199 always
  // P-gen work assignment: thread -> (row rP, 8 consecutive k)
  int rP = t >> 2;                       // 0..63
  int kq = (t & 3) * 8;                  // 0,8,16,24
  int bP = b0 + rP;
  int iP = bP / NV;
  int jP = bP - iP * NV;
  int iselP = iP - i0;                   // 0 or 1
  float4v acc[2][8];
#pragma unroll
  for (int m = 0; m < 2; ++m)
#pragma unroll
    for (int n = 0; n < 8; ++n) acc[m][n] = (float4v)(0.f);

  for (int h = 0; h < NH; ++h) {
    __syncthreads();  // all waves done reading S1i/S2i/CijS of previous head
    if (t < 224) {
      bool v = t < NV;
      int o0 = h * NN + i0 * NV + t;
      int o1 = h * NN + i1 * NV + t;
      S1i[0][t] = v ? SC1[o0] : 0.f;
      S2i[0][t] = v ? SC2[o0] : 0.f;
      S1i[1][t] = v ? SC1[o1] : 0.f;
      S2i[1][t] = v ? SC2[o1] : 0.f;
    }
    if (t < 64) {
      int b = b0 + t;
      int ii = b / NV, jv = b - ii * NV;
      CijS[t] = C[h * NN + b];
      CjiS[t] = C[h * NN + jv * NV + ii];
    }
    __syncthreads();
    float ci = CijS[rP], cj = CjiS[rP];
    const float* pj1 = SC1 + h * NN + jP * NV;
    const float* pj2 = SC2 + h * NN + jP * NV;
    const ushort* zb = ZT + h * 224;

    for (int ks = 0; ks < 7; ++ks) {
      // --- issue B-tile loads early (L2 latency hides under exp2) ---
      uint4 bq[4];
#pragma unroll
      for (int qq = 0; qq < 4; ++qq) {
        int li = qq * 256 + t;           // 0..1023
        int c = li >> 2;                 // 0..255
        int ko = (li & 3) * 8;           // 0,8,16,24 (ushorts)
        bq[qq] = *(const uint4*)(zb + (size_t)(c0 + c) * 896 + ks * 32 + ko);
      }
      // --- P values: this thread's row rP, k = kb..kb+7 ---
      int kb = ks * 32 + kq;
      uint4 pk = make_uint4(0, 0, 0, 0);
      if (kb < NV) {                     // NV%8==0: granule fully valid or not
        float4 a1 = *(const float4*)(pj1 + kb);
        float4 a1b = *(const float4*)(pj1 + kb + 4);
        float4 a2 = *(const float4*)(pj2 + kb);
        float4 a2b = *(const float4*)(pj2 + kb + 4);
        float4 t1 = *(const float4*)&S1i[iselP][kb];
        float4 t1b = *(const float4*)&S1i[iselP][kb + 4];
        float4 u1 = *(const float4*)&S2i[iselP][kb];
        float4 u1b = *(const float4*)&S2i[iselP][kb + 4];
        float p0 = exp2f(t1.x + a2.x - ci) + exp2f(a1.x + u1.x - cj);
        float p1 = exp2f(t1.y + a2.y - ci) + exp2f(a1.y + u1.y - cj);
        float p2 = exp2f(t1.z + a2.z - ci) + exp2f(a1.z + u1.z - cj);
        float p3 = exp2f(t1.w + a2.w - ci) + exp2f(a1.w + u1.w - cj);
        float p4 = exp2f(t1b.x + a2b.x - ci) + exp2f(a1b.x + u1b.x - cj);
        float p5 = exp2f(t1b.y + a2b.y - ci) + exp2f(a1b.y + u1b.y - cj);
        float p6 = exp2f(t1b.z + a2b.z - ci) + exp2f(a1b.z + u1b.z - cj);
        float p7 = exp2f(t1b.w + a2b.w - ci) + exp2f(a1b.w + u1b.w - cj);
        pk = make_uint4(packbf(p0, p1), packbf(p2, p3),
                        packbf(p4, p5), packbf(p6, p7));
      }
      __syncthreads();  // previous step's MFMA reads of As/Bs complete
      *(uint4*)&As[rP * 40 + kq] = pk;
#pragma unroll
      for (int qq = 0; qq < 4; ++qq) {
        int li = qq * 256 + t;
        int c = li >> 2;
        int ko = (li & 3) * 8;
        *(uint4*)&Bs[c * 40 + ko] = bq[qq];
      }
      __syncthreads();
      // --- MFMA: 2 m-frags x 8 n-frags per wave ---
      short8v af0 = *(const short8v*)&As[(wr * 32 + frow) * 40 + quad * 8];
      short8v af1 = *(const short8v*)&As[(wr * 32 + 16 + frow) * 40 + quad * 8];
#pragma unroll
      for (int n = 0; n < 8; ++n) {
        int cb = wcb + n * 16;
        if (c0 + cb < DM) {              // wave-uniform: skip dead col frags
          short8v bf = *(const short8v*)&Bs[(cb + frow) * 40 + quad * 8];
          acc[0][n] = __builtin_amdgcn_mfma_f32_16x16x32_bf16(af0, bf,
                                                              acc[0][n], 0, 0, 0);
          acc[1][n] = __builtin_amdgcn_mfma_f32_16x16x32_bf16(af1, bf,
                                                              acc[1][n], 0, 0, 0);
        }
      }
    }
  }
  // epilogue: C/D layout col=lane&15, row=quad*4+reg
#pragma unroll
  for (int n = 0; n < 8; ++n) {
    int c = c0 + wcb + n * 16 + frow;
    if (c >= DM) continue;
    float bb = 2.0f * b3[c];
#pragma unroll
    for (int m = 0; m < 2; ++m) {
      int bbase = b0 + wr * 32 + m * 16 + quad * 4;
#pragma unroll
      for (int r2 = 0; r2 < 4; ++r2) {
        outS[(size_t)(bbase + r2) * DM + c] = acc[m][n][r2] + bb;
      }
    }
  }
}

// ---------------------------------------------------------------------------
// G: Q_sa = relu(S@v1+b1)@v2 + b2
// ---------------------------------------------------------------------------
__global__ __launch_bounds__(256) void k_qsa(
    const float* __restrict__ S, const float* __restrict__ v1w,
    const float* __restrict__ v1b, const float* __restrict__ v2w,
    const float* __restrict__ v2b, float* __restrict__ outQ) {
  __shared__ float Ss[64][9];
  __shared__ float V1s[8][48];
  __shared__ float Ts[64][49];
  int t = threadIdx.x;
  int b0 = blockIdx.x * 64;
  int ty = t >> 4, tx = t & 15;
  int lr = t >> 2, lk = (t & 3) * 2;
  float acc[4][3];
#pragma unroll
  for (int y = 0; y < 4; y++)
#pragma unroll
    for (int xx = 0; xx < 3; xx++) acc[y][xx] = 0.f;
  for (int k0 = 0; k0 < DM; k0 += 8) {
    __syncthreads();
    Ss[lr][lk] = S[(size_t)(b0 + lr) * DM + k0 + lk];
    Ss[lr][lk + 1] = S[(size_t)(b0 + lr) * DM + k0 + lk + 1];
    if (t < 192) {
      int e = t * 2; int kk = e / 48, c = e - kk * 48;
      V1s[kk][c] = v1w[(k0 + kk) * 48 + c];
      V1s[kk][c + 1] = v1w[(k0 + kk) * 48 + c + 1];
    }
    __syncthreads();
#pragma unroll
    for (int kk = 0; kk < 8; kk++) {
      float a0 = Ss[ty * 4 + 0][kk], a1 = Ss[ty * 4 + 1][kk],
            a2 = Ss[ty * 4 + 2][kk], a3 = Ss[ty * 4 + 3][kk];
      float w0_ = V1s[kk][tx * 3 + 0], w1_ = V1s[kk][tx * 3 + 1],
            w2_ = V1s[kk][tx * 3 + 2];
      acc[0][0] += a0 * w0_; acc[0][1] += a0 * w1_; acc[0][2] += a0 * w2_;
      acc[1][0] += a1 * w0_; acc[1][1] += a1 * w1_; acc[1][2] += a1 * w2_;
      acc[2][0] += a2 * w0_; acc[2][1] += a2 * w1_; acc[2][2] += a2 * w2_;
      acc[3][0] += a3 * w0_; acc[3][1] += a3 * w1_; acc[3][2] += a3 * w2_;
    }
  }
#pragma unroll
  for (int y = 0; y < 4; y++)
#pragma unroll
    for (int xx = 0; xx < 3; xx++)
      Ts[ty * 4 + y][tx * 3 + xx] = fmaxf(acc[y][xx] + v1b[tx * 3 + xx], 0.f);
  __syncthreads();
  if (t < 64) {
    float q = v2b[0];
    for (int c = 0; c < 48; c++) q += Ts[t][c] * v2w[c];
    outQ[b0 + t] = q;
  }
}

// ---------------------------------------------------------------------------
extern "C" void kernel_launch(void* const* d_in, const int* in_sizes, int n_in,
                              void* d_out, int out_size, void* d_ws,
                              size_t ws_size, hipStream_t stream) {
  const float* x = (const float*)d_in[0];
  const float* label = (const float*)d_in[1];
  const float* h0 = (const float*)d_in[2];
  const float* w = (const float*)d_in[3];
  const float* dmat = (const float*)d_in[4];
  const float* l0w = (const float*)d_in[5];
  const float* l0b = (const float*)d_in[6];
  const float* l1w = (const float*)d_in[7];
  const float* l1b = (const float*)d_in[8];
  const float* l2w = (const float*)d_in[9];
  const float* l2b = (const float*)d_in[10];
  const float* l3w = (const float*)d_in[11];
  const float* l3b = (const float*)d_in[12];
  const float* l4w = (const float*)d_in[13];
  const float* l4b = (const float*)d_in[14];
  const float* l5w = (const float*)d_in[15];
  const float* l5b = (const float*)d_in[16];
  const float* w0 = (const float*)d_in[17];
  const float* b0v = (const float*)d_in[18];
  const float* w1 = (const float*)d_in[19];
  const float* b1v = (const float*)d_in[20];
  const float* w3 = (const float*)d_in[21];
  const float* b3 = (const float*)d_in[22];
  const float* v1w = (const float*)d_in[23];
  const float* v1b = (const float*)d_in[24];
  const float* v2w = (const float*)d_in[25];
  const float* v2b = (const float*)d_in[26];
  const int* remain_step = (const int*)d_in[29];

  float* ws = (float*)d_ws;
  float* base = ws + WS_BASE;
  float* h1 = ws + WS_H1;
  float* h2 = ws + WS_H2;
  float* hfull = ws + WS_HFULL;
  float* gmean = ws + WS_GMEAN;
  float* W0s = ws + WS_W0S;
  float* W1s = ws + WS_W1S;
  float* khf = ws + WS_KHF;
  float* vhf = ws + WS_VHF;
  float* B1 = ws + WS_B1;
  float* B2 = ws + WS_B2;
  float* SC1 = ws + WS_SC1;
  float* SC2 = ws + WS_SC2;
  float* Z = ws + WS_Z;
  ushort* ZT = (ushort*)(ws + WS_ZT);
  float* C = ws + WS_B1;  // reuses B1/B2 slots after k_SC

  float* outS = (float*)d_out;
  float* outH = outS + OFF_H;
  float* outHF = outS + OFF_HF;
  float* outQ = outS + OFF_Q;

  k_base<<<NV, 256, 0, stream>>>(x, dmat, label, l0w, l0b, l1w, l1b, l2b, l3b,
                                 l4w, l4b, l5w, l5b, base);
  k_gcn<<<NV, 192, 0, stream>>>(h0, base, w, l2w, l3w, h1);
  k_gcn<<<NV, 192, 0, stream>>>(h1, base, w, l2w, l3w, h2);
  k_hfull<<<NV, 128, 0, stream>>>(h2, x, label, remain_step, hfull, outH, outHF);
  k_gmean<<<KG, 128, 0, stream>>>(hfull, gmean);
  k_wsum<<<(HD * DM + 255) / 256, 256, 0, stream>>>(w0, w1, W0s, W1s);
  k_kv<<<NV, 256, 0, stream>>>(hfull, W0s, b0v, W1s, b1v, khf, vhf);
  k_Z<<<dim3(NV, NH), 256, 0, stream>>>(vhf, w3, Z);
  k_ZT<<<(512 * 896 + 255) / 256, 256, 0, stream>>>(Z, ZT);
  k_B<<<NV, 256, 0, stream>>>(hfull, gmean, w0, b0v, B1, B2);
  k_SC<<<NV, 256, 0, stream>>>(B1, B2, khf, SC1, SC2);
  k_ml<<<dim3(NV, NH), 256, 0, stream>>>(SC1, SC2, C);
  k_sfused3<<<dim3(2, 625), 256, 0, stream>>>(SC1, SC2, C, ZT, b3, outS);
  k_qsa<<<NN / 64, 256, 0, stream>>>(outS, v1w, v1b, v2w, v2b, outQ);
}

// Round 3
// 579.460 us; speedup vs baseline: 1.3527x; 1.2238x over previous
//
#include <hip/hip_runtime.h>
#include <hip/hip_bf16.h>
#include <math.h>

typedef unsigned short ushort;
typedef unsigned int uint;

// Sizes (fixed by the reference problem)
#define NV 200     // N nodes
#define DEG 199
#define HID 96
#define KG 20      // groups / one-hot width
#define MG 10      // group size
#define AJR 30
#define NH 4
#define HD 118     // HID + 2 + K
#define DM 472     // NH*HD
#define NN 40000   // N*N
#define NT 20100   // N*(N+1)/2 unique (i<=j) pairs: S[(i,j)] == S[(j,i)]

// Workspace layout (float units).
#define WS_BASE   0
#define WS_H1     19200
#define WS_H2     38400
#define WS_HFULL  57600
#define WS_GMEAN  81200
#define WS_W0S    83560
#define WS_W1S    139256
#define WS_KHF    194952
#define WS_VHF    289352
#define WS_B1     383752  // after k_SC: reused for C (softmax row consts, 160000 floats)
#define WS_B2     478152
#define WS_SC1    572552
#define WS_SC2    732552
#define WS_Z      892552             // Z fp32: 4*224*472 = 422,912 floats
#define WS_ZT     1315464            // ZT bf16: 512*896 ushorts = 229,376 floats

// Output layout (floats)
#define OFF_H   18880000
#define OFF_HF  18899200
#define OFF_Q   18922800

typedef __attribute__((ext_vector_type(8))) short short8v;
typedef __attribute__((ext_vector_type(4))) float float4v;

__device__ __forceinline__ float bf2f(uint u) {
  return __uint_as_float(u << 16);
}
__device__ __forceinline__ ushort f2bf(float f) {
  uint u = __float_as_uint(f);
  uint r = (u + 0x7fffu + ((u >> 16) & 1u)) >> 16;  // RNE
  return (ushort)r;
}
__device__ __forceinline__ uint packbf(float a, float b) {
  __hip_bfloat162 h2 = __float22bfloat162_rn(make_float2(a, b));
  union { __hip_bfloat162 h; uint u; } c;
  c.h = h2;
  return c.u;
}

// Packed upper-triangle index p (0..NT-1) -> (i,j), i<=j.
// off(i) = i*200 - i*(i-1)/2; i from closed form + fixup for float slop.
__device__ __forceinline__ int triOff(int i) {
  return i * 200 - ((i * (i - 1)) >> 1);
}
__device__ __forceinline__ void p2ij(int p, int& io, int& jo) {
  float s = sqrtf((float)(160801 - 8 * p));   // (2N+1)^2 - 8p
  int i = (int)((401.0f - s) * 0.5f);
  if (i < 0) i = 0;
  if (i > 199) i = 199;
  while (i > 0 && triOff(i) > p) --i;
  while (i < 199 && triOff(i + 1) <= p) ++i;
  io = i;
  jo = i + (p - triOff(i));
}

// ---------------------------------------------------------------------------
// A: iteration-invariant part of the GCN update
// ---------------------------------------------------------------------------
__global__ __launch_bounds__(256) void k_base(
    const float* __restrict__ x, const float* __restrict__ dmat,
    const float* __restrict__ label,
    const float* __restrict__ l0w, const float* __restrict__ l0b,
    const float* __restrict__ l1w, const float* __restrict__ l1b,
    const float* __restrict__ l2b, const float* __restrict__ l3b,
    const float* __restrict__ l4w, const float* __restrict__ l4b,
    const float* __restrict__ l5w, const float* __restrict__ l5b,
    float* __restrict__ base) {
  int i = blockIdx.x; int t = threadIdx.x;
  int g = i / MG;
  __shared__ float sv[256];
  __shared__ float sn2[9];
  float v = -1.0f;
  if (t < DEG) {
    int u = (t < i) ? t : t + 1;
    if (u / MG != g) v = dmat[i * DEG + t];
  }
  sv[t] = v;
  __syncthreads();
  for (int k2 = 2; k2 <= 256; k2 <<= 1) {
    for (int jj = k2 >> 1; jj > 0; jj >>= 1) {
      int ixj = t ^ jj;
      if (ixj > t) {
        float a = sv[t], b = sv[ixj];
        bool sw = ((t & k2) == 0) ? (a < b) : (a > b);
        if (sw) { sv[t] = b; sv[ixj] = a; }
      }
      __syncthreads();
    }
  }
  if (t == 0) {
    float tmp[9];
    for (int q = 0; q < 9; q++) tmp[q] = dmat[i * DEG + MG * g + q];
    for (int a2 = 1; a2 < 9; a2++) {
      float key = tmp[a2]; int b2 = a2 - 1;
      while (b2 >= 0 && tmp[b2] < key) { tmp[b2 + 1] = tmp[b2]; b2--; }
      tmp[b2 + 1] = key;
    }
    for (int q = 0; q < 9; q++) sn2[q] = tmp[q];
  }
  __syncthreads();
  if (t < HID) {
    float acc = l0b[t] + l1b[t] + l2b[t] + l3b[t] + l4b[t] + l5b[t];
    acc += x[i * 2 + 0] * l0w[t] + x[i * 2 + 1] * l0w[HID + t];
    for (int k = 0; k < KG; k++) acc += label[i * KG + k] * l1w[k * HID + t];
    for (int q = 0; q < AJR; q++) acc += sv[q] * l4w[q * HID + t];
    for (int q = 0; q < 9; q++) acc += sn2[q] * l5w[q * HID + t];
    base[i * HID + t] = acc;
  }
}

// ---------------------------------------------------------------------------
// B: one GCN step
// ---------------------------------------------------------------------------
__global__ __launch_bounds__(192) void k_gcn(
    const float* __restrict__ hin, const float* __restrict__ base,
    const float* __restrict__ w, const float* __restrict__ l2w,
    const float* __restrict__ l3w, float* __restrict__ hout) {
  int i = blockIdx.x; int t = threadIdx.x;
  int g = i / MG;
  __shared__ float n1[HID], n2[HID];
  if (t < HID) {
    float acc = 0.f, wsum = 0.f;
    for (int j = 0; j < DEG; j++) {
      int u = (j < i) ? j : j + 1;
      if (u / MG != g) {
        float wj = w[i * DEG + j];
        acc += wj * hin[u * HID + t];
        wsum += wj;
      }
    }
    n1[t] = acc / wsum;
  } else if (t < 2 * HID) {
    int dd = t - HID;
    float acc = 0.f, wsum = 0.f;
    for (int u = MG * g; u < MG * g + MG; u++) {
      if (u == i) continue;
      int j = (u < i) ? u : u - 1;
      float wj = w[i * DEG + j];
      acc += wj * hin[u * HID + dd];
      wsum += wj;
    }
    n2[dd] = acc / wsum;
  }
  __syncthreads();
  if (t < HID) {
    float acc = base[i * HID + t];
    for (int dd = 0; dd < HID; dd++)
      acc += n1[dd] * l2w[dd * HID + t] + n2[dd] * l3w[dd * HID + t];
    hout[i * HID + t] = fmaxf(acc, 0.f);
  }
}

// ---------------------------------------------------------------------------
// C1: h_full assembly (+ h, h_full outputs)
// ---------------------------------------------------------------------------
__global__ __launch_bounds__(128) void k_hfull(
    const float* __restrict__ h, const float* __restrict__ x,
    const float* __restrict__ label, const int* __restrict__ remain_step,
    float* __restrict__ hfull, float* __restrict__ out_h,
    float* __restrict__ out_hf) {
  int i = blockIdx.x; int t = threadIdx.x;
  if (t < HD) {
    float v;
    if (t < HID) {
      int p = *remain_step;
      int t2 = t & ~1;
      float div = expf(-(float)t2 * (logf(10000.f) / (float)HID));
      float ang = (float)p * div;
      float pe = (t & 1) ? cosf(ang) : sinf(ang);
      float hv = h[i * HID + t];
      out_h[i * HID + t] = hv;
      v = hv + pe;
    } else if (t < HID + 2) {
      v = x[i * 2 + (t - HID)];
    } else {
      v = label[i * KG + (t - HID - 2)];
    }
    hfull[i * HD + t] = v;
    out_hf[i * HD + t] = v;
  }
}

// C2: group means of h_full
__global__ __launch_bounds__(128) void k_gmean(
    const float* __restrict__ hfull, float* __restrict__ gmean) {
  int g = blockIdx.x; int t = threadIdx.x;
  if (t < HD) {
    float s = 0.f;
    for (int q = 0; q < MG; q++) s += hfull[(g * MG + q) * HD + t];
    gmean[g * HD + t] = s * 0.1f;
  }
}

// D1: sum of the 4 118-row blocks of mha_w{0,1}
__global__ __launch_bounds__(256) void k_wsum(
    const float* __restrict__ w0, const float* __restrict__ w1,
    float* __restrict__ W0s, float* __restrict__ W1s) {
  int idx = blockIdx.x * blockDim.x + threadIdx.x;
  if (idx < HD * DM) {
    int dp = idx / DM, c = idx - dp * DM;
    W0s[idx] = w0[dp * DM + c] + w0[(HD + dp) * DM + c] +
               w0[(2 * HD + dp) * DM + c] + w0[(3 * HD + dp) * DM + c];
    W1s[idx] = w1[dp * DM + c] + w1[(HD + dp) * DM + c] +
               w1[(2 * HD + dp) * DM + c] + w1[(3 * HD + dp) * DM + c];
  }
}

// D2: khf / vhf
__global__ __launch_bounds__(256) void k_kv(
    const float* __restrict__ hfull, const float* __restrict__ W0s,
    const float* __restrict__ b0v, const float* __restrict__ W1s,
    const float* __restrict__ b1v, float* __restrict__ khf,
    float* __restrict__ vhf) {
  int i = blockIdx.x; int t = threadIdx.x;
  __shared__ float hr[HD];
  if (t < HD) hr[t] = hfull[i * HD + t];
  __syncthreads();
  for (int c = t; c < DM; c += 256) {
    float a0 = b0v[c], a1 = b1v[c];
    for (int dd = 0; dd < HD; dd++) {
      float hv = hr[dd];
      a0 += hv * W0s[dd * DM + c];
      a1 += hv * W1s[dd * DM + c];
    }
    khf[i * DM + c] = a0;
    vhf[i * DM + c] = a1;
  }
}

// D3: B1/B2 (query decomposition)
__global__ __launch_bounds__(256) void k_B(
    const float* __restrict__ hfull, const float* __restrict__ gmean,
    const float* __restrict__ w0, const float* __restrict__ b0v,
    float* __restrict__ B1, float* __restrict__ B2) {
  int i = blockIdx.x; int t = threadIdx.x; int g = i / MG;
  __shared__ float hr[HD], gr[HD];
  if (t < HD) { hr[t] = hfull[i * HD + t]; gr[t] = gmean[g * HD + t]; }
  __syncthreads();
  for (int c = t; c < DM; c += 256) {
    float a1 = 0.f, a2 = b0v[c];
    for (int dd = 0; dd < HD; dd++) {
      a1 += hr[dd] * w0[dd * DM + c] + gr[dd] * w0[(2 * HD + dd) * DM + c];
      a2 += hr[dd] * w0[(HD + dd) * DM + c] + gr[dd] * w0[(3 * HD + dd) * DM + c];
    }
    B1[i * DM + c] = a1;
    B2[i * DM + c] = a2;
  }
}

// D4: score components SC1/SC2, pre-scaled by (1/sqrt(HD))*log2(e)
__global__ __launch_bounds__(256) void k_SC(
    const float* __restrict__ B1, const float* __restrict__ B2,
    const float* __restrict__ khf, float* __restrict__ SC1,
    float* __restrict__ SC2) {
  int i = blockIdx.x; int t = threadIdx.x;
  const float scl = 1.4426950408889634f / sqrtf((float)HD);
  __shared__ float b1r[DM], b2r[DM];
  for (int c = t; c < DM; c += 256) { b1r[c] = B1[i * DM + c]; b2r[c] = B2[i * DM + c]; }
  __syncthreads();
  for (int p = t; p < NH * NV; p += 256) {
    int h = p / NV, k = p - h * NV;
    float s1a = 0.f, s2a = 0.f;
    for (int dd = 0; dd < HD; dd++) {
      float kv = khf[k * DM + h * HD + dd];
      s1a += b1r[h * HD + dd] * kv;
      s2a += b2r[h * HD + dd] * kv;
    }
    SC1[h * NN + i * NV + k] = s1a * scl;
    SC2[h * NN + i * NV + k] = s2a * scl;
  }
}

// D5: softmax row constants C[h][i][j] = m + log2(l), coalesced row scans.
__global__ __launch_bounds__(256) void k_ml(
    const float* __restrict__ SC1, const float* __restrict__ SC2,
    float* __restrict__ C) {
  int i = blockIdx.x, h = blockIdx.y;
  int t = threadIdx.x;
  __shared__ float s1s[224];
  for (int k = t; k < 224; k += 256)
    s1s[k] = (k < NV) ? SC1[h * NN + i * NV + k] : -1e30f;
  __syncthreads();
  int l = t & 31;
  int g = t >> 5;
  const float* s2b = SC2 + h * NN;
  for (int it = 0; it < 25; ++it) {
    int j = it * 8 + g;
    const float* row = s2b + j * NV;
    float v[7];
#pragma unroll
    for (int e = 0; e < 7; ++e) {
      int k = l + 32 * e;
      v[e] = (k < NV) ? (s1s[k] + row[k]) : -1e30f;
    }
    float m = v[0];
#pragma unroll
    for (int e = 1; e < 7; ++e) m = fmaxf(m, v[e]);
#pragma unroll
    for (int off = 16; off > 0; off >>= 1) m = fmaxf(m, __shfl_xor(m, off, 32));
    float s = 0.f;
#pragma unroll
    for (int e = 0; e < 7; ++e) s += exp2f(v[e] - m);
#pragma unroll
    for (int off = 16; off > 0; off >>= 1) s += __shfl_xor(s, off, 32);
    if (l == 0) C[h * NN + i * NV + j] = m + log2f(s);
  }
}

// ---------------------------------------------------------------------------
// E1: Z[h][k][c] = sum_d vhf[k][h*HD+d] * w3[(h*HD+d)*DM + c]  (fp32)
// Grid (NV, NH).
// ---------------------------------------------------------------------------
__global__ __launch_bounds__(256) void k_Z(
    const float* __restrict__ vhf, const float* __restrict__ w3,
    float* __restrict__ Z) {
  int k = blockIdx.x, h = blockIdx.y;
  int t = threadIdx.x;
  __shared__ float vr[HD];
  if (t < HD) vr[t] = vhf[k * DM + h * HD + t];
  __syncthreads();
  for (int c = t; c < DM; c += 256) {
    float a = 0.f;
    for (int d = 0; d < HD; ++d) a += vr[d] * w3[(h * HD + d) * DM + c];
    Z[((size_t)h * 224 + k) * DM + c] = a;
  }
}

// E2: ZT[c][h*224+kk] = bf16(Z[h][kk][c]) zero-padded (c>=472 or kk>=200). 512x896.
__global__ __launch_bounds__(256) void k_ZT(
    const float* __restrict__ Z, ushort* __restrict__ ZT) {
  int idx = blockIdx.x * 256 + threadIdx.x;  // < 512*896
  if (idx < 512 * 896) {
    int c = idx / 896, kp = idx - c * 896;
    int h = kp / 224, kk = kp - h * 224;
    ushort v = 0;
    if (c < DM && kk < NV) v = f2bf(Z[((size_t)h * 224 + kk) * DM + c]);
    ZT[idx] = v;
  }
}

// ---------------------------------------------------------------------------
// F (v4): fused attention+output GEMM over UNIQUE row pairs.
// S[(i,j)][c] = sum_{h,k} [exp2(SC1[h,i,k]+SC2[h,j,k]-C[h,i,j])
//                        + exp2(SC1[h,j,k]+SC2[h,i,k]-C[h,j,i])] * Z[h][k][c]
//             + 2*b3[c]
// KEY FACT: this expression is symmetric in i<->j, so S[(i,j)] == S[(j,i)].
// v4 = v1's proven structure (in-register A-frag gen, 128 rows x 128 cols,
// 4 waves, 2 barriers/ks) iterating over packed upper-triangle indices
// p in [0, NT): exactly half the MFMA + exp2 work of v1; the epilogue writes
// each row to both (i,j) and (j,i). All four SC rows are loaded from global
// (SC arrays are 1.3 MB -> L2-resident), replacing v1's LDS S1i staging at
// the same live-register count. Grid (4, ceil(NT/128)=158).
// ---------------------------------------------------------------------------
__global__ __launch_bounds__(256) void k_sfusedT(
    const float* __restrict__ SC1, const float* __restrict__ SC2,
    const float* __restrict__ C, const ushort* __restrict__ ZT,
    const float* __restrict__ b3, float* __restrict__ outS) {
  int t = threadIdx.x;
  int c0 = blockIdx.x * 128, p0 = blockIdx.y * 128;
  int lane = t & 63, wm = t >> 6;
  int frow = lane & 15, quad = lane >> 4;
  __shared__ __align__(16) ushort Bs[128 * 40];
  // this lane's two A-frag rows (packed indices)
  bool bval[2]; int iN[2], jN[2], iA[2], jA[2];
#pragma unroll
  for (int m = 0; m < 2; ++m) {
    int p = p0 + wm * 32 + m * 16 + frow;
    bval[m] = (p < NT);
    int ii = 0, jj = 0;
    if (bval[m]) p2ij(p, ii, jj);
    iA[m] = ii; jA[m] = jj;
    iN[m] = ii * NV; jN[m] = jj * NV;
  }
  float4v acc[2][8];
#pragma unroll
  for (int m = 0; m < 2; ++m)
#pragma unroll
    for (int n = 0; n < 8; ++n) acc[m][n] = (float4v)(0.f);
  int rB = t >> 1, khB = (t & 1) * 16;

  for (int h = 0; h < NH; ++h) {
    int hb = h * NN;
    const float* s1h = SC1 + hb;
    const float* s2h = SC2 + hb;
    float ci[2], cj[2];
#pragma unroll
    for (int m = 0; m < 2; ++m) {
      ci[m] = bval[m] ? C[hb + iN[m] + jA[m]] : 0.f;
      cj[m] = bval[m] ? C[hb + jN[m] + iA[m]] : 0.f;
    }
    for (int ks = 0; ks < 7; ++ks) {
      int kb = ks * 32 + quad * 8;
      bool kvalid = (kb + 7 < NV);  // uniform per (ks,quad); ks=6,quad=0 -> 192..199 ok
      // --- generate A fragments in-register ---
      union { uint4 q; short8v v; } af[2];
#pragma unroll
      for (int m = 0; m < 2; ++m) {
        if (bval[m] && kvalid) {
          const float* q1i = s1h + iN[m] + kb;
          const float* q2i = s2h + iN[m] + kb;
          const float* q1j = s1h + jN[m] + kb;
          const float* q2j = s2h + jN[m] + kb;
          float4 a0 = *(const float4*)q1i,       a0b = *(const float4*)(q1i + 4);
          float4 b0 = *(const float4*)(q2j),     b0b = *(const float4*)(q2j + 4);
          float4 d0 = *(const float4*)(q1j),     d0b = *(const float4*)(q1j + 4);
          float4 e0 = *(const float4*)(q2i),     e0b = *(const float4*)(q2i + 4);
          float cim = ci[m], cjm = cj[m];
          float p0_ = exp2f(a0.x + b0.x - cim) + exp2f(d0.x + e0.x - cjm);
          float p1_ = exp2f(a0.y + b0.y - cim) + exp2f(d0.y + e0.y - cjm);
          float p2_ = exp2f(a0.z + b0.z - cim) + exp2f(d0.z + e0.z - cjm);
          float p3_ = exp2f(a0.w + b0.w - cim) + exp2f(d0.w + e0.w - cjm);
          float p4_ = exp2f(a0b.x + b0b.x - cim) + exp2f(d0b.x + e0b.x - cjm);
          float p5_ = exp2f(a0b.y + b0b.y - cim) + exp2f(d0b.y + e0b.y - cjm);
          float p6_ = exp2f(a0b.z + b0b.z - cim) + exp2f(d0b.z + e0b.z - cjm);
          float p7_ = exp2f(a0b.w + b0b.w - cim) + exp2f(d0b.w + e0b.w - cjm);
          af[m].q.x = packbf(p0_, p1_);
          af[m].q.y = packbf(p2_, p3_);
          af[m].q.z = packbf(p4_, p5_);
          af[m].q.w = packbf(p6_, p7_);
        } else {
          af[m].q = make_uint4(0, 0, 0, 0);
        }
      }
      // --- stage B tile (Z^T slice) ---
      const uint4* wp = (const uint4*)(ZT + (size_t)(c0 + rB) * 896 +
                                       h * 224 + ks * 32 + khB);
      uint4 bq0 = wp[0], bq1 = wp[1];
      __syncthreads();
      *(uint4*)&Bs[rB * 40 + khB] = bq0;
      *(uint4*)&Bs[rB * 40 + khB + 8] = bq1;
      __syncthreads();
      // --- MFMA ---
#pragma unroll
      for (int n = 0; n < 8; ++n) {
        short8v bf = *(const short8v*)&Bs[(n * 16 + frow) * 40 + quad * 8];
        acc[0][n] = __builtin_amdgcn_mfma_f32_16x16x32_bf16(af[0].v, bf,
                                                            acc[0][n], 0, 0, 0);
        acc[1][n] = __builtin_amdgcn_mfma_f32_16x16x32_bf16(af[1].v, bf,
                                                            acc[1][n], 0, 0, 0);
      }
    }
  }
  // epilogue: C/D layout col=lane&15, row=quad*4+reg. Each packed row is
  // written to (i,j) and, when i!=j, mirrored to (j,i).
  int ie[2][4], je[2][4];
#pragma unroll
  for (int m = 0; m < 2; ++m)
#pragma unroll
    for (int r2 = 0; r2 < 4; ++r2) {
      int pe = p0 + wm * 32 + m * 16 + quad * 4 + r2;
      if (pe < NT) {
        p2ij(pe, ie[m][r2], je[m][r2]);
      } else {
        ie[m][r2] = -1; je[m][r2] = 0;
      }
    }
#pragma unroll
  for (int n = 0; n < 8; ++n) {
    int c = c0 + n * 16 + frow;
    if (c >= DM) continue;
    float bb = 2.0f * b3[c];
#pragma unroll
    for (int m = 0; m < 2; ++m) {
#pragma unroll
      for (int r2 = 0; r2 < 4; ++r2) {
        int ii = ie[m][r2];
        if (ii < 0) continue;
        int jj = je[m][r2];
        float v = acc[m][n][r2] + bb;
        outS[(size_t)(ii * NV + jj) * DM + c] = v;
        if (ii != jj) outS[(size_t)(jj * NV + ii) * DM + c] = v;
      }
    }
  }
}

// ---------------------------------------------------------------------------
// G (v4): Q_sa = relu(S@v1+b1)@v2 + b2, over unique (i<=j) rows; Q_sa is
// symmetric like S, so the scalar is mirrored to (j,i).
// ---------------------------------------------------------------------------
__global__ __launch_bounds__(256) void k_qsaT(
    const float* __restrict__ S, const float* __restrict__ v1w,
    const float* __restrict__ v1b, const float* __restrict__ v2w,
    const float* __restrict__ v2b, float* __restrict__ outQ) {
  __shared__ float Ss[64][9];
  __shared__ float V1s[8][48];
  __shared__ float Ts[64][49];
  __shared__ int rowI[64], rowJ[64];
  int t = threadIdx.x;
  int p0b = blockIdx.x * 64;
  if (t < 64) {
    int p = p0b + t;
    if (p < NT) {
      int ii, jj; p2ij(p, ii, jj);
      rowI[t] = ii; rowJ[t] = jj;
    } else {
      rowI[t] = -1; rowJ[t] = 0;
    }
  }
  int ty = t >> 4, tx = t & 15;
  int lr = t >> 2, lk = (t & 3) * 2;
  __syncthreads();
  int riS = rowI[lr];
  size_t srow = (riS >= 0) ? (size_t)(riS * NV + rowJ[lr]) * DM : 0;
  float acc[4][3];
#pragma unroll
  for (int y = 0; y < 4; y++)
#pragma unroll
    for (int xx = 0; xx < 3; xx++) acc[y][xx] = 0.f;
  for (int k0 = 0; k0 < DM; k0 += 8) {
    __syncthreads();
    Ss[lr][lk] = S[srow + k0 + lk];
    Ss[lr][lk + 1] = S[srow + k0 + lk + 1];
    if (t < 192) {
      int e = t * 2; int kk = e / 48, c = e - kk * 48;
      V1s[kk][c] = v1w[(k0 + kk) * 48 + c];
      V1s[kk][c + 1] = v1w[(k0 + kk) * 48 + c + 1];
    }
    __syncthreads();
#pragma unroll
    for (int kk = 0; kk < 8; kk++) {
      float a0 = Ss[ty * 4 + 0][kk], a1 = Ss[ty * 4 + 1][kk],
            a2 = Ss[ty * 4 + 2][kk], a3 = Ss[ty * 4 + 3][kk];
      float w0_ = V1s[kk][tx * 3 + 0], w1_ = V1s[kk][tx * 3 + 1],
            w2_ = V1s[kk][tx * 3 + 2];
      acc[0][0] += a0 * w0_; acc[0][1] += a0 * w1_; acc[0][2] += a0 * w2_;
      acc[1][0] += a1 * w0_; acc[1][1] += a1 * w1_; acc[1][2] += a1 * w2_;
      acc[2][0] += a2 * w0_; acc[2][1] += a2 * w1_; acc[2][2] += a2 * w2_;
      acc[3][0] += a3 * w0_; acc[3][1] += a3 * w1_; acc[3][2] += a3 * w2_;
    }
  }
#pragma unroll
  for (int y = 0; y < 4; y++)
#pragma unroll
    for (int xx = 0; xx < 3; xx++)
      Ts[ty * 4 + y][tx * 3 + xx] = fmaxf(acc[y][xx] + v1b[tx * 3 + xx], 0.f);
  __syncthreads();
  if (t < 64 && rowI[t] >= 0) {
    float q = v2b[0];
    for (int c = 0; c < 48; c++) q += Ts[t][c] * v2w[c];
    int ii = rowI[t], jj = rowJ[t];
    outQ[ii * NV + jj] = q;
    if (ii != jj) outQ[jj * NV + ii] = q;
  }
}

// ---------------------------------------------------------------------------
extern "C" void kernel_launch(void* const* d_in, const int* in_sizes, int n_in,
                              void* d_out, int out_size, void* d_ws,
                              size_t ws_size, hipStream_t stream) {
  const float* x = (const float*)d_in[0];
  const float* label = (const float*)d_in[1];
  const float* h0 = (const float*)d_in[2];
  const float* w = (const float*)d_in[3];
  const float* dmat = (const float*)d_in[4];
  const float* l0w = (const float*)d_in[5];
  const float* l0b = (const float*)d_in[6];
  const float* l1w = (const float*)d_in[7];
  const float* l1b = (const float*)d_in[8];
  const float* l2w = (const float*)d_in[9];
  const float* l2b = (const float*)d_in[10];
  const float* l3w = (const float*)d_in[11];
  const float* l3b = (const float*)d_in[12];
  const float* l4w = (const float*)d_in[13];
  const float* l4b = (const float*)d_in[14];
  const float* l5w = (const float*)d_in[15];
  const float* l5b = (const float*)d_in[16];
  const float* w0 = (const float*)d_in[17];
  const float* b0v = (const float*)d_in[18];
  const float* w1 = (const float*)d_in[19];
  const float* b1v = (const float*)d_in[20];
  const float* w3 = (const float*)d_in[21];
  const float* b3 = (const float*)d_in[22];
  const float* v1w = (const float*)d_in[23];
  const float* v1b = (const float*)d_in[24];
  const float* v2w = (const float*)d_in[25];
  const float* v2b = (const float*)d_in[26];
  const int* remain_step = (const int*)d_in[29];

  float* ws = (float*)d_ws;
  float* base = ws + WS_BASE;
  float* h1 = ws + WS_H1;
  float* h2 = ws + WS_H2;
  float* hfull = ws + WS_HFULL;
  float* gmean = ws + WS_GMEAN;
  float* W0s = ws + WS_W0S;
  float* W1s = ws + WS_W1S;
  float* khf = ws + WS_KHF;
  float* vhf = ws + WS_VHF;
  float* B1 = ws + WS_B1;
  float* B2 = ws + WS_B2;
  float* SC1 = ws + WS_SC1;
  float* SC2 = ws + WS_SC2;
  float* Z = ws + WS_Z;
  ushort* ZT = (ushort*)(ws + WS_ZT);
  float* C = ws + WS_B1;  // reuses B1/B2 slots after k_SC

  float* outS = (float*)d_out;
  float* outH = outS + OFF_H;
  float* outHF = outS + OFF_HF;
  float* outQ = outS + OFF_Q;

  k_base<<<NV, 256, 0, stream>>>(x, dmat, label, l0w, l0b, l1w, l1b, l2b, l3b,
                                 l4w, l4b, l5w, l5b, base);
  k_gcn<<<NV, 192, 0, stream>>>(h0, base, w, l2w, l3w, h1);
  k_gcn<<<NV, 192, 0, stream>>>(h1, base, w, l2w, l3w, h2);
  k_hfull<<<NV, 128, 0, stream>>>(h2, x, label, remain_step, hfull, outH, outHF);
  k_gmean<<<KG, 128, 0, stream>>>(hfull, gmean);
  k_wsum<<<(HD * DM + 255) / 256, 256, 0, stream>>>(w0, w1, W0s, W1s);
  k_kv<<<NV, 256, 0, stream>>>(hfull, W0s, b0v, W1s, b1v, khf, vhf);
  k_Z<<<dim3(NV, NH), 256, 0, stream>>>(vhf, w3, Z);
  k_ZT<<<(512 * 896 + 255) / 256, 256, 0, stream>>>(Z, ZT);
  k_B<<<NV, 256, 0, stream>>>(hfull, gmean, w0, b0v, B1, B2);
  k_SC<<<NV, 256, 0, stream>>>(B1, B2, khf, SC1, SC2);
  k_ml<<<dim3(NV, NH), 256, 0, stream>>>(SC1, SC2, C);
  k_sfusedT<<<dim3(4, (NT + 127) / 128), 256, 0, stream>>>(SC1, SC2, C, ZT, b3,
                                                           outS);
  k_qsaT<<<(NT + 63) / 64, 256, 0, stream>>>(outS, v1w, v1b, v2w, v2b, outQ);
}

// Round 4
// 573.804 us; speedup vs baseline: 1.3660x; 1.0099x over previous
//
#include <hip/hip_runtime.h>
#include <hip/hip_bf16.h>
#include <math.h>

typedef unsigned short ushort;
typedef unsigned int uint;

// Sizes (fixed by the reference problem)
#define NV 200     // N nodes
#define DEG 199
#define HID 96
#define KG 20      // groups / one-hot width
#define MG 10      // group size
#define AJR 30
#define NH 4
#define HD 118     // HID + 2 + K
#define DM 472     // NH*HD
#define NN 40000   // N*N
#define NT 20100   // N*(N+1)/2 unique (i<=j) pairs: S[(i,j)] == S[(j,i)]

// Workspace layout (float units).
#define WS_BASE   0
#define WS_H1     19200
#define WS_H2     38400
#define WS_HFULL  57600
#define WS_GMEAN  81200
#define WS_KHF    194952   // khfT [DM][NV] = 94400 floats (transposed!)
#define WS_VHF    289352
#define WS_B1     383752   // after k_SC: reused for C (softmax row consts)
#define WS_B2     478152
#define WS_SC1    572552
#define WS_SC2    732552
#define WS_Z      892552             // Z fp32: 4*224*472 = 422,912 floats
#define WS_ZT     1315464            // ZT bf16: 512*896 ushorts

// Output layout (floats)
#define OFF_H   18880000
#define OFF_HF  18899200
#define OFF_Q   18922800

typedef __attribute__((ext_vector_type(8))) short short8v;
typedef __attribute__((ext_vector_type(4))) float float4v;

__device__ __forceinline__ float bf2f(uint u) {
  return __uint_as_float(u << 16);
}
__device__ __forceinline__ ushort f2bf(float f) {
  uint u = __float_as_uint(f);
  uint r = (u + 0x7fffu + ((u >> 16) & 1u)) >> 16;  // RNE
  return (ushort)r;
}
__device__ __forceinline__ uint packbf(float a, float b) {
  __hip_bfloat162 h2 = __float22bfloat162_rn(make_float2(a, b));
  union { __hip_bfloat162 h; uint u; } c;
  c.h = h2;
  return c.u;
}

// Packed upper-triangle index p (0..NT-1) -> (i,j), i<=j.
__device__ __forceinline__ int triOff(int i) {
  return i * 200 - ((i * (i - 1)) >> 1);
}
__device__ __forceinline__ void p2ij(int p, int& io, int& jo) {
  float s = sqrtf((float)(160801 - 8 * p));   // (2N+1)^2 - 8p
  int i = (int)((401.0f - s) * 0.5f);
  if (i < 0) i = 0;
  if (i > 199) i = 199;
  while (i > 0 && triOff(i) > p) --i;
  while (i < 199 && triOff(i + 1) <= p) ++i;
  io = i;
  jo = i + (p - triOff(i));
}

// ---------------------------------------------------------------------------
// A: iteration-invariant part of the GCN update
// ---------------------------------------------------------------------------
__global__ __launch_bounds__(256) void k_base(
    const float* __restrict__ x, const float* __restrict__ dmat,
    const float* __restrict__ label,
    const float* __restrict__ l0w, const float* __restrict__ l0b,
    const float* __restrict__ l1w, const float* __restrict__ l1b,
    const float* __restrict__ l2b, const float* __restrict__ l3b,
    const float* __restrict__ l4w, const float* __restrict__ l4b,
    const float* __restrict__ l5w, const float* __restrict__ l5b,
    float* __restrict__ base) {
  int i = blockIdx.x; int t = threadIdx.x;
  int g = i / MG;
  __shared__ float sv[256];
  __shared__ float sn2[9];
  float v = -1.0f;
  if (t < DEG) {
    int u = (t < i) ? t : t + 1;
    if (u / MG != g) v = dmat[i * DEG + t];
  }
  sv[t] = v;
  __syncthreads();
  for (int k2 = 2; k2 <= 256; k2 <<= 1) {
    for (int jj = k2 >> 1; jj > 0; jj >>= 1) {
      int ixj = t ^ jj;
      if (ixj > t) {
        float a = sv[t], b = sv[ixj];
        bool sw = ((t & k2) == 0) ? (a < b) : (a > b);
        if (sw) { sv[t] = b; sv[ixj] = a; }
      }
      __syncthreads();
    }
  }
  if (t == 0) {
    float tmp[9];
    for (int q = 0; q < 9; q++) tmp[q] = dmat[i * DEG + MG * g + q];
    for (int a2 = 1; a2 < 9; a2++) {
      float key = tmp[a2]; int b2 = a2 - 1;
      while (b2 >= 0 && tmp[b2] < key) { tmp[b2 + 1] = tmp[b2]; b2--; }
      tmp[b2 + 1] = key;
    }
    for (int q = 0; q < 9; q++) sn2[q] = tmp[q];
  }
  __syncthreads();
  if (t < HID) {
    float acc = l0b[t] + l1b[t] + l2b[t] + l3b[t] + l4b[t] + l5b[t];
    acc += x[i * 2 + 0] * l0w[t] + x[i * 2 + 1] * l0w[HID + t];
    for (int k = 0; k < KG; k++) acc += label[i * KG + k] * l1w[k * HID + t];
    for (int q = 0; q < AJR; q++) acc += sv[q] * l4w[q * HID + t];
    for (int q = 0; q < 9; q++) acc += sn2[q] * l5w[q * HID + t];
    base[i * HID + t] = acc;
  }
}

// ---------------------------------------------------------------------------
// B: one GCN step
// ---------------------------------------------------------------------------
__global__ __launch_bounds__(192) void k_gcn(
    const float* __restrict__ hin, const float* __restrict__ base,
    const float* __restrict__ w, const float* __restrict__ l2w,
    const float* __restrict__ l3w, float* __restrict__ hout) {
  int i = blockIdx.x; int t = threadIdx.x;
  int g = i / MG;
  __shared__ float n1[HID], n2[HID];
  if (t < HID) {
    float acc = 0.f, wsum = 0.f;
    for (int j = 0; j < DEG; j++) {
      int u = (j < i) ? j : j + 1;
      if (u / MG != g) {
        float wj = w[i * DEG + j];
        acc += wj * hin[u * HID + t];
        wsum += wj;
      }
    }
    n1[t] = acc / wsum;
  } else if (t < 2 * HID) {
    int dd = t - HID;
    float acc = 0.f, wsum = 0.f;
    for (int u = MG * g; u < MG * g + MG; u++) {
      if (u == i) continue;
      int j = (u < i) ? u : u - 1;
      float wj = w[i * DEG + j];
      acc += wj * hin[u * HID + dd];
      wsum += wj;
    }
    n2[dd] = acc / wsum;
  }
  __syncthreads();
  if (t < HID) {
    float acc = base[i * HID + t];
    for (int dd = 0; dd < HID; dd++)
      acc += n1[dd] * l2w[dd * HID + t] + n2[dd] * l3w[dd * HID + t];
    hout[i * HID + t] = fmaxf(acc, 0.f);
  }
}

// ---------------------------------------------------------------------------
// C1: h_full assembly (+ h, h_full outputs)
// ---------------------------------------------------------------------------
__global__ __launch_bounds__(128) void k_hfull(
    const float* __restrict__ h, const float* __restrict__ x,
    const float* __restrict__ label, const int* __restrict__ remain_step,
    float* __restrict__ hfull, float* __restrict__ out_h,
    float* __restrict__ out_hf) {
  int i = blockIdx.x; int t = threadIdx.x;
  if (t < HD) {
    float v;
    if (t < HID) {
      int p = *remain_step;
      int t2 = t & ~1;
      float div = expf(-(float)t2 * (logf(10000.f) / (float)HID));
      float ang = (float)p * div;
      float pe = (t & 1) ? cosf(ang) : sinf(ang);
      float hv = h[i * HID + t];
      out_h[i * HID + t] = hv;
      v = hv + pe;
    } else if (t < HID + 2) {
      v = x[i * 2 + (t - HID)];
    } else {
      v = label[i * KG + (t - HID - 2)];
    }
    hfull[i * HD + t] = v;
    out_hf[i * HD + t] = v;
  }
}

// C2: group means of h_full
__global__ __launch_bounds__(128) void k_gmean(
    const float* __restrict__ hfull, float* __restrict__ gmean) {
  int g = blockIdx.x; int t = threadIdx.x;
  if (t < HD) {
    float s = 0.f;
    for (int q = 0; q < MG; q++) s += hfull[(g * MG + q) * HD + t];
    gmean[g * HD + t] = s * 0.1f;
  }
}

// ---------------------------------------------------------------------------
// D (v5): fused k_wsum + k_kv + k_B.
// Per (i, c): d_q = hr . w0blk(q), g_q = gr . w0blk(q), e_q = hr . w1blk(q):
//   khfT[c][i] = b0v[c] + d0+d1+d2+d3        (khf TRANSPOSED for k_SC reads)
//   vhf[i][c]  = b1v[c] + e0+e1+e2+e3
//   B1[i][c]   = d0 + g2
//   B2[i][c]   = b0v[c] + d1 + g3
// Eliminates W0s/W1s intermediates and two launches.
// ---------------------------------------------------------------------------
__global__ __launch_bounds__(256) void k_kvB(
    const float* __restrict__ hfull, const float* __restrict__ gmean,
    const float* __restrict__ w0, const float* __restrict__ b0v,
    const float* __restrict__ w1, const float* __restrict__ b1v,
    float* __restrict__ khfT, float* __restrict__ vhf,
    float* __restrict__ B1, float* __restrict__ B2) {
  int i = blockIdx.x; int t = threadIdx.x; int g = i / MG;
  __shared__ float hr[HD], gr[HD];
  if (t < HD) { hr[t] = hfull[i * HD + t]; gr[t] = gmean[g * HD + t]; }
  __syncthreads();
  for (int c = t; c < DM; c += 256) {
    const float* w0c = w0 + c;
    const float* w1c = w1 + c;
    float d0 = 0.f, d1 = 0.f, d2 = 0.f, d3 = 0.f;
    float g2 = 0.f, g3 = 0.f;
    float e0 = 0.f, e1 = 0.f, e2 = 0.f, e3 = 0.f;
    for (int dd = 0; dd < HD; dd++) {
      float hv = hr[dd], gv = gr[dd];
      float a0 = w0c[dd * DM];
      float a1 = w0c[(HD + dd) * DM];
      float a2 = w0c[(2 * HD + dd) * DM];
      float a3 = w0c[(3 * HD + dd) * DM];
      d0 += hv * a0; d1 += hv * a1; d2 += hv * a2; d3 += hv * a3;
      g2 += gv * a2; g3 += gv * a3;
      e0 += hv * w1c[dd * DM];
      e1 += hv * w1c[(HD + dd) * DM];
      e2 += hv * w1c[(2 * HD + dd) * DM];
      e3 += hv * w1c[(3 * HD + dd) * DM];
    }
    float b0c = b0v[c];
    khfT[c * NV + i] = b0c + d0 + d1 + d2 + d3;
    vhf[i * DM + c] = b1v[c] + e0 + e1 + e2 + e3;
    B1[i * DM + c] = d0 + g2;
    B2[i * DM + c] = b0c + d1 + g3;
  }
}

// D4 (v5): score components; khfT is [c][k] so the k-gather is coalesced
// across threads (k consecutive per lane). Pre-scaled by (1/sqrt(HD))*log2(e).
__global__ __launch_bounds__(256) void k_SC(
    const float* __restrict__ B1, const float* __restrict__ B2,
    const float* __restrict__ khfT, float* __restrict__ SC1,
    float* __restrict__ SC2) {
  int i = blockIdx.x; int t = threadIdx.x;
  const float scl = 1.4426950408889634f / sqrtf((float)HD);
  __shared__ float b1r[DM], b2r[DM];
  for (int c = t; c < DM; c += 256) { b1r[c] = B1[i * DM + c]; b2r[c] = B2[i * DM + c]; }
  __syncthreads();
  for (int p = t; p < NH * NV; p += 256) {
    int h = p / NV, k = p - h * NV;
    float s1a = 0.f, s2a = 0.f;
    const float* kc = khfT + (size_t)h * HD * NV + k;
    const float* b1h = b1r + h * HD;
    const float* b2h = b2r + h * HD;
    for (int dd = 0; dd < HD; dd++) {
      float kv = kc[dd * NV];
      s1a += b1h[dd] * kv;
      s2a += b2h[dd] * kv;
    }
    SC1[h * NN + i * NV + k] = s1a * scl;
    SC2[h * NN + i * NV + k] = s2a * scl;
  }
}

// D5: softmax row constants C[h][i][j] = m + log2(l), coalesced row scans.
__global__ __launch_bounds__(256) void k_ml(
    const float* __restrict__ SC1, const float* __restrict__ SC2,
    float* __restrict__ C) {
  int i = blockIdx.x, h = blockIdx.y;
  int t = threadIdx.x;
  __shared__ float s1s[224];
  for (int k = t; k < 224; k += 256)
    s1s[k] = (k < NV) ? SC1[h * NN + i * NV + k] : -1e30f;
  __syncthreads();
  int l = t & 31;
  int g = t >> 5;
  const float* s2b = SC2 + h * NN;
  for (int it = 0; it < 25; ++it) {
    int j = it * 8 + g;
    const float* row = s2b + j * NV;
    float v[7];
#pragma unroll
    for (int e = 0; e < 7; ++e) {
      int k = l + 32 * e;
      v[e] = (k < NV) ? (s1s[k] + row[k]) : -1e30f;
    }
    float m = v[0];
#pragma unroll
    for (int e = 1; e < 7; ++e) m = fmaxf(m, v[e]);
#pragma unroll
    for (int off = 16; off > 0; off >>= 1) m = fmaxf(m, __shfl_xor(m, off, 32));
    float s = 0.f;
#pragma unroll
    for (int e = 0; e < 7; ++e) s += exp2f(v[e] - m);
#pragma unroll
    for (int off = 16; off > 0; off >>= 1) s += __shfl_xor(s, off, 32);
    if (l == 0) C[h * NN + i * NV + j] = m + log2f(s);
  }
}

// ---------------------------------------------------------------------------
// E1: Z[h][k][c] = sum_d vhf[k][h*HD+d] * w3[(h*HD+d)*DM + c]  (fp32)
// ---------------------------------------------------------------------------
__global__ __launch_bounds__(256) void k_Z(
    const float* __restrict__ vhf, const float* __restrict__ w3,
    float* __restrict__ Z) {
  int k = blockIdx.x, h = blockIdx.y;
  int t = threadIdx.x;
  __shared__ float vr[HD];
  if (t < HD) vr[t] = vhf[k * DM + h * HD + t];
  __syncthreads();
  for (int c = t; c < DM; c += 256) {
    float a = 0.f;
    for (int d = 0; d < HD; ++d) a += vr[d] * w3[(h * HD + d) * DM + c];
    Z[((size_t)h * 224 + k) * DM + c] = a;
  }
}

// E2: ZT[c][h*224+kk] = bf16(Z[h][kk][c]) zero-padded. 512x896.
__global__ __launch_bounds__(256) void k_ZT(
    const float* __restrict__ Z, ushort* __restrict__ ZT) {
  int idx = blockIdx.x * 256 + threadIdx.x;  // < 512*896
  if (idx < 512 * 896) {
    int c = idx / 896, kp = idx - c * 896;
    int h = kp / 224, kk = kp - h * 224;
    ushort v = 0;
    if (c < DM && kk < NV) v = f2bf(Z[((size_t)h * 224 + kk) * DM + c]);
    ZT[idx] = v;
  }
}

// ---------------------------------------------------------------------------
// F (v5): fused attention+output GEMM over UNIQUE row pairs, 64-row tiles.
// Same math as v4 (symmetric S), but tile = 64 packed rows x 128 cols,
// grid (4, 315) = 1260 blocks (~5/CU vs v4's 2.5): TLP hides the exp2 +
// barrier latency that capped v4 at VALUBusy 40% / occupancy 20%.
// Each wave owns 16 rows (one A-frag) x 128 cols; acc[8] = 32 VGPR.
// ---------------------------------------------------------------------------
__global__ __launch_bounds__(256) void k_sfusedT2(
    const float* __restrict__ SC1, const float* __restrict__ SC2,
    const float* __restrict__ C, const ushort* __restrict__ ZT,
    const float* __restrict__ b3, float* __restrict__ outS) {
  int t = threadIdx.x;
  int c0 = blockIdx.x * 128, p0 = blockIdx.y * 64;
  int lane = t & 63, wm = t >> 6;
  int frow = lane & 15, quad = lane >> 4;
  __shared__ __align__(16) ushort Bs[128 * 40];
  // this lane's A-frag row (packed index)
  int p = p0 + wm * 16 + frow;
  bool bval = (p < NT);
  int iA = 0, jA = 0;
  if (bval) p2ij(p, iA, jA);
  int iN = iA * NV, jN = jA * NV;
  float4v acc[8];
#pragma unroll
  for (int n = 0; n < 8; ++n) acc[n] = (float4v)(0.f);
  int rB = t >> 1, khB = (t & 1) * 16;

  for (int h = 0; h < NH; ++h) {
    int hb = h * NN;
    const float* s1h = SC1 + hb;
    const float* s2h = SC2 + hb;
    float ci = bval ? C[hb + iN + jA] : 0.f;
    float cj = bval ? C[hb + jN + iA] : 0.f;
    for (int ks = 0; ks < 7; ++ks) {
      int kb = ks * 32 + quad * 8;
      bool kvalid = (kb + 7 < NV);
      // --- generate A fragment in-register ---
      union { uint4 q; short8v v; } af;
      if (bval && kvalid) {
        const float* q1i = s1h + iN + kb;
        const float* q2i = s2h + iN + kb;
        const float* q1j = s1h + jN + kb;
        const float* q2j = s2h + jN + kb;
        float4 a0 = *(const float4*)q1i,   a0b = *(const float4*)(q1i + 4);
        float4 b0 = *(const float4*)q2j,   b0b = *(const float4*)(q2j + 4);
        float4 d0 = *(const float4*)q1j,   d0b = *(const float4*)(q1j + 4);
        float4 e0 = *(const float4*)q2i,   e0b = *(const float4*)(q2i + 4);
        float p0_ = exp2f(a0.x + b0.x - ci) + exp2f(d0.x + e0.x - cj);
        float p1_ = exp2f(a0.y + b0.y - ci) + exp2f(d0.y + e0.y - cj);
        float p2_ = exp2f(a0.z + b0.z - ci) + exp2f(d0.z + e0.z - cj);
        float p3_ = exp2f(a0.w + b0.w - ci) + exp2f(d0.w + e0.w - cj);
        float p4_ = exp2f(a0b.x + b0b.x - ci) + exp2f(d0b.x + e0b.x - cj);
        float p5_ = exp2f(a0b.y + b0b.y - ci) + exp2f(d0b.y + e0b.y - cj);
        float p6_ = exp2f(a0b.z + b0b.z - ci) + exp2f(d0b.z + e0b.z - cj);
        float p7_ = exp2f(a0b.w + b0b.w - ci) + exp2f(d0b.w + e0b.w - cj);
        af.q.x = packbf(p0_, p1_);
        af.q.y = packbf(p2_, p3_);
        af.q.z = packbf(p4_, p5_);
        af.q.w = packbf(p6_, p7_);
      } else {
        af.q = make_uint4(0, 0, 0, 0);
      }
      // --- stage B tile (Z^T slice) ---
      const uint4* wp = (const uint4*)(ZT + (size_t)(c0 + rB) * 896 +
                                       h * 224 + ks * 32 + khB);
      uint4 bq0 = wp[0], bq1 = wp[1];
      __syncthreads();
      *(uint4*)&Bs[rB * 40 + khB] = bq0;
      *(uint4*)&Bs[rB * 40 + khB + 8] = bq1;
      __syncthreads();
      // --- MFMA ---
#pragma unroll
      for (int n = 0; n < 8; ++n) {
        short8v bf = *(const short8v*)&Bs[(n * 16 + frow) * 40 + quad * 8];
        acc[n] = __builtin_amdgcn_mfma_f32_16x16x32_bf16(af.v, bf, acc[n],
                                                         0, 0, 0);
      }
    }
  }
  // epilogue: C/D layout col=lane&15, row=quad*4+reg; mirror to (j,i).
  int ie[4], je[4];
#pragma unroll
  for (int r2 = 0; r2 < 4; ++r2) {
    int pe = p0 + wm * 16 + quad * 4 + r2;
    if (pe < NT) {
      p2ij(pe, ie[r2], je[r2]);
    } else {
      ie[r2] = -1; je[r2] = 0;
    }
  }
#pragma unroll
  for (int n = 0; n < 8; ++n) {
    int c = c0 + n * 16 + frow;
    if (c >= DM) continue;
    float bb = 2.0f * b3[c];
#pragma unroll
    for (int r2 = 0; r2 < 4; ++r2) {
      int ii = ie[r2];
      if (ii < 0) continue;
      int jj = je[r2];
      float v = acc[n][r2] + bb;
      outS[(size_t)(ii * NV + jj) * DM + c] = v;
      if (ii != jj) outS[(size_t)(jj * NV + ii) * DM + c] = v;
    }
  }
}

// ---------------------------------------------------------------------------
// G: Q_sa = relu(S@v1+b1)@v2 + b2, over unique (i<=j) rows; mirrored.
// ---------------------------------------------------------------------------
__global__ __launch_bounds__(256) void k_qsaT(
    const float* __restrict__ S, const float* __restrict__ v1w,
    const float* __restrict__ v1b, const float* __restrict__ v2w,
    const float* __restrict__ v2b, float* __restrict__ outQ) {
  __shared__ float Ss[64][9];
  __shared__ float V1s[8][48];
  __shared__ float Ts[64][49];
  __shared__ int rowI[64], rowJ[64];
  int t = threadIdx.x;
  int p0b = blockIdx.x * 64;
  if (t < 64) {
    int p = p0b + t;
    if (p < NT) {
      int ii, jj; p2ij(p, ii, jj);
      rowI[t] = ii; rowJ[t] = jj;
    } else {
      rowI[t] = -1; rowJ[t] = 0;
    }
  }
  int ty = t >> 4, tx = t & 15;
  int lr = t >> 2, lk = (t & 3) * 2;
  __syncthreads();
  int riS = rowI[lr];
  size_t srow = (riS >= 0) ? (size_t)(riS * NV + rowJ[lr]) * DM : 0;
  float acc[4][3];
#pragma unroll
  for (int y = 0; y < 4; y++)
#pragma unroll
    for (int xx = 0; xx < 3; xx++) acc[y][xx] = 0.f;
  for (int k0 = 0; k0 < DM; k0 += 8) {
    __syncthreads();
    Ss[lr][lk] = S[srow + k0 + lk];
    Ss[lr][lk + 1] = S[srow + k0 + lk + 1];
    if (t < 192) {
      int e = t * 2; int kk = e / 48, c = e - kk * 48;
      V1s[kk][c] = v1w[(k0 + kk) * 48 + c];
      V1s[kk][c + 1] = v1w[(k0 + kk) * 48 + c + 1];
    }
    __syncthreads();
#pragma unroll
    for (int kk = 0; kk < 8; kk++) {
      float a0 = Ss[ty * 4 + 0][kk], a1 = Ss[ty * 4 + 1][kk],
            a2 = Ss[ty * 4 + 2][kk], a3 = Ss[ty * 4 + 3][kk];
      float w0_ = V1s[kk][tx * 3 + 0], w1_ = V1s[kk][tx * 3 + 1],
            w2_ = V1s[kk][tx * 3 + 2];
      acc[0][0] += a0 * w0_; acc[0][1] += a0 * w1_; acc[0][2] += a0 * w2_;
      acc[1][0] += a1 * w0_; acc[1][1] += a1 * w1_; acc[1][2] += a1 * w2_;
      acc[2][0] += a2 * w0_; acc[2][1] += a2 * w1_; acc[2][2] += a2 * w2_;
      acc[3][0] += a3 * w0_; acc[3][1] += a3 * w1_; acc[3][2] += a3 * w2_;
    }
  }
#pragma unroll
  for (int y = 0; y < 4; y++)
#pragma unroll
    for (int xx = 0; xx < 3; xx++)
      Ts[ty * 4 + y][tx * 3 + xx] = fmaxf(acc[y][xx] + v1b[tx * 3 + xx], 0.f);
  __syncthreads();
  if (t < 64 && rowI[t] >= 0) {
    float q = v2b[0];
    for (int c = 0; c < 48; c++) q += Ts[t][c] * v2w[c];
    int ii = rowI[t], jj = rowJ[t];
    outQ[ii * NV + jj] = q;
    if (ii != jj) outQ[jj * NV + ii] = q;
  }
}

// ---------------------------------------------------------------------------
extern "C" void kernel_launch(void* const* d_in, const int* in_sizes, int n_in,
                              void* d_out, int out_size, void* d_ws,
                              size_t ws_size, hipStream_t stream) {
  const float* x = (const float*)d_in[0];
  const float* label = (const float*)d_in[1];
  const float* h0 = (const float*)d_in[2];
  const float* w = (const float*)d_in[3];
  const float* dmat = (const float*)d_in[4];
  const float* l0w = (const float*)d_in[5];
  const float* l0b = (const float*)d_in[6];
  const float* l1w = (const float*)d_in[7];
  const float* l1b = (const float*)d_in[8];
  const float* l2w = (const float*)d_in[9];
  const float* l2b = (const float*)d_in[10];
  const float* l3w = (const float*)d_in[11];
  const float* l3b = (const float*)d_in[12];
  const float* l4w = (const float*)d_in[13];
  const float* l4b = (const float*)d_in[14];
  const float* l5w = (const float*)d_in[15];
  const float* l5b = (const float*)d_in[16];
  const float* w0 = (const float*)d_in[17];
  const float* b0v = (const float*)d_in[18];
  const float* w1 = (const float*)d_in[19];
  const float* b1v = (const float*)d_in[20];
  const float* w3 = (const float*)d_in[21];
  const float* b3 = (const float*)d_in[22];
  const float* v1w = (const float*)d_in[23];
  const float* v1b = (const float*)d_in[24];
  const float* v2w = (const float*)d_in[25];
  const float* v2b = (const float*)d_in[26];
  const int* remain_step = (const int*)d_in[29];

  float* ws = (float*)d_ws;
  float* base = ws + WS_BASE;
  float* h1 = ws + WS_H1;
  float* h2 = ws + WS_H2;
  float* hfull = ws + WS_HFULL;
  float* gmean = ws + WS_GMEAN;
  float* khfT = ws + WS_KHF;
  float* vhf = ws + WS_VHF;
  float* B1 = ws + WS_B1;
  float* B2 = ws + WS_B2;
  float* SC1 = ws + WS_SC1;
  float* SC2 = ws + WS_SC2;
  float* Z = ws + WS_Z;
  ushort* ZT = (ushort*)(ws + WS_ZT);
  float* C = ws + WS_B1;  // reuses B1/B2 slots after k_SC

  float* outS = (float*)d_out;
  float* outH = outS + OFF_H;
  float* outHF = outS + OFF_HF;
  float* outQ = outS + OFF_Q;

  k_base<<<NV, 256, 0, stream>>>(x, dmat, label, l0w, l0b, l1w, l1b, l2b, l3b,
                                 l4w, l4b, l5w, l5b, base);
  k_gcn<<<NV, 192, 0, stream>>>(h0, base, w, l2w, l3w, h1);
  k_gcn<<<NV, 192, 0, stream>>>(h1, base, w, l2w, l3w, h2);
  k_hfull<<<NV, 128, 0, stream>>>(h2, x, label, remain_step, hfull, outH, outHF);
  k_gmean<<<KG, 128, 0, stream>>>(hfull, gmean);
  k_kvB<<<NV, 256, 0, stream>>>(hfull, gmean, w0, b0v, w1, b1v, khfT, vhf, B1,
                                B2);
  k_Z<<<dim3(NV, NH), 256, 0, stream>>>(vhf, w3, Z);
  k_ZT<<<(512 * 896 + 255) / 256, 256, 0, stream>>>(Z, ZT);
  k_SC<<<NV, 256, 0, stream>>>(B1, B2, khfT, SC1, SC2);
  k_ml<<<dim3(NV, NH), 256, 0, stream>>>(SC1, SC2, C);
  k_sfusedT2<<<dim3(4, (NT + 63) / 64), 256, 0, stream>>>(SC1, SC2, C, ZT, b3,
                                                          outS);
  k_qsaT<<<(NT + 63) / 64, 256, 0, stream>>>(outS, v1w, v1b, v2w, v2b, outQ);
}